// Round 9
// baseline (1075.343 us; speedup 1.0000x reference)
//
#include <hip/hip_runtime.h>
#include <stdint.h>

// ---------------- problem constants ----------------
#define NB    2048
#define NAG   8
#define NEXP  4
#define LN_EPS 1e-5f

#define OUT_GATES  (2048*101)            // 206848
#define OUT_LBL    (OUT_GATES + 2048*4)  // 215040

typedef __attribute__((ext_vector_type(8))) short short8;
typedef __attribute__((ext_vector_type(4))) float f32x4;

#define MFMA_BF16(a,b,c) __builtin_amdgcn_mfma_f32_16x16x32_bf16((a),(b),(c),0,0,0)

__device__ __forceinline__ float bf2f(unsigned short h){
  union { unsigned int u; float f; } v; v.u = ((unsigned int)h) << 16; return v.f;
}
__device__ __forceinline__ unsigned short f2bf(float x){
  union { float f; unsigned int u; } v; v.f = x;
  unsigned int r = v.u + 0x7FFFu + ((v.u >> 16) & 1u);
  return (unsigned short)(r >> 16);
}
union bfpack8 { short8 v; unsigned short u[8]; };

// async global->LDS DMA, 16B per lane; LDS dest = wave-uniform base + lane*16
__device__ __forceinline__ void gload16(const void* g, void* l){
  __builtin_amdgcn_global_load_lds(
      (const __attribute__((address_space(1))) void*)g,
      (__attribute__((address_space(3))) void*)l, 16, 0, 0);
}

// raw barrier with compiler memory fences (no vmcnt drain!)
#define FBAR() do{ asm volatile("" ::: "memory"); \
                   __builtin_amdgcn_s_barrier(); \
                   asm volatile("" ::: "memory"); }while(0)

// ---------------- workspace layout (bytes) ----------------
#define OFF_WQKVT  0ULL                      // [4][1536][512] bf16
#define OFF_WOT    6291456ULL                // [4][512][512]
#define OFF_WF1T   8388608ULL                // [4][2048][512]
#define OFF_WF2T   16777216ULL               // [4][512][2048]
#define OFF_HW1T   25165824ULL               // [512][4096]
#define OFF_HW2T   29360128ULL               // [112][512] (zero-padded rows)
#define OFF_XBF    29474816ULL               // [4096][8][512] bf16 (x after LN1); MIXEDBF overlays after FFN
#define OFF_SLOTO  63029248ULL               // [4096][4096] bf16 per-slot LN2 out
#define OFF_HID    96583680ULL               // [2048][512] bf16
#define OFF_JOBS   98680832ULL               // int[4][2048] slot ids (slot=b*2+s)
#define OFF_SLOTW  98713600ULL               // float[4096] gate weight per slot
#define OFF_LSE    98729984ULL               // float[2048]
#define OFF_CNT    98738176ULL               // int[4]
#define WS_NEED    98738192ULL

// ============ transpose+cast: src f32 [E][R][C] -> dst bf16 [E][C][R] ============
__global__ __launch_bounds__(256) void k_transpose_cast(const float* __restrict__ src,
    unsigned short* __restrict__ dst, int R, int C){
  __shared__ float tile[32][33];
  int e = blockIdx.z;
  int c0 = blockIdx.x*32, r0 = blockIdx.y*32;
  const float* s = src + (size_t)e*R*C;
  unsigned short* d = dst + (size_t)e*C*R;
  int tx = threadIdx.x & 31, ty = threadIdx.x >> 5;
  for(int yy = ty; yy < 32; yy += 8){
    int r = r0+yy, c = c0+tx;
    if(r<R && c<C) tile[yy][tx] = s[(size_t)r*C + c];
  }
  __syncthreads();
  for(int yy = ty; yy < 32; yy += 8){
    int oc = c0+yy, orr = r0+tx;
    if(oc<C && orr<R) d[(size_t)oc*R + orr] = f2bf(tile[tx][yy]);
  }
}

// ============ router: logits, top2 gates, job lists, lse ============
__global__ __launch_bounds__(256) void k_router(const float* __restrict__ lat,
    const float* __restrict__ act, const float* __restrict__ gateW,
    float* __restrict__ gates_out, int* __restrict__ jobs, int* __restrict__ cnt,
    float* __restrict__ slot_w, float* __restrict__ lse_arr){
  int b = blockIdx.x, t = threadIdx.x;
  float a0=0.f,a1=0.f,a2=0.f,a3=0.f;
  for(int i=t;i<4096;i+=256){
    int n=i>>9, d=i&511;
    float v = (d<256)? lat[((size_t)b*8+n)*256 + d] : act[((size_t)b*8+n)*256 + (d-256)];
    float4 gw = *(const float4*)&gateW[(size_t)i*4];
    a0 += v*gw.x; a1 += v*gw.y; a2 += v*gw.z; a3 += v*gw.w;
  }
  __shared__ float red[4][256];
  red[0][t]=a0; red[1][t]=a1; red[2][t]=a2; red[3][t]=a3;
  __syncthreads();
  for(int s=128;s>0;s>>=1){
    if(t<s){ red[0][t]+=red[0][t+s]; red[1][t]+=red[1][t+s]; red[2][t]+=red[2][t+s]; red[3][t]+=red[3][t+s]; }
    __syncthreads();
  }
  if(t==0){
    float lg[4] = {red[0][0], red[1][0], red[2][0], red[3][0]};
    int i1=0; for(int e=1;e<4;e++) if(lg[e]>lg[i1]) i1=e;
    int i2=-1; for(int e=0;e<4;e++){ if(e==i1) continue; if(i2<0 || lg[e]>lg[i2]) i2=e; }
    float m = lg[i1];
    float e2 = __expf(lg[i2]-m);
    float inv = 1.f/(1.f+e2);
    float w1 = inv, w2 = e2*inv;
    float g[4]={0.f,0.f,0.f,0.f}; g[i1]=w1; g[i2]=w2;
    gates_out[b*4+0]=g[0]; gates_out[b*4+1]=g[1]; gates_out[b*4+2]=g[2]; gates_out[b*4+3]=g[3];
    float s=0.f; for(int e=0;e<4;e++) s += __expf(lg[e]-m);
    lse_arr[b] = m + __logf(s);
    int p1 = atomicAdd(&cnt[i1],1); jobs[i1*2048+p1] = b*2+0; slot_w[b*2+0] = w1;
    int p2 = atomicAdd(&cnt[i2],1); jobs[i2*2048+p2] = b*2+1; slot_w[b*2+1] = w2;
  }
}

// ============ finalize: load-balance loss ============
__global__ __launch_bounds__(256) void k_finalize(const float* __restrict__ gates,
    const float* __restrict__ lse_arr, const int* __restrict__ cnt, float* __restrict__ lbl){
  __shared__ float r0[256], r1[256], r2[256], r3[256], rl[256];
  int t = threadIdx.x;
  float g0=0.f,g1=0.f,g2=0.f,g3=0.f,l=0.f;
  for(int b=t;b<2048;b+=256){
    g0+=gates[b*4+0]; g1+=gates[b*4+1]; g2+=gates[b*4+2]; g3+=gates[b*4+3];
    l += lse_arr[b];
  }
  r0[t]=g0;r1[t]=g1;r2[t]=g2;r3[t]=g3;rl[t]=l;
  __syncthreads();
  for(int s=128;s>0;s>>=1){
    if(t<s){ r0[t]+=r0[t+s]; r1[t]+=r1[t+s]; r2[t]+=r2[t+s]; r3[t]+=r3[t+s]; rl[t]+=rl[t+s]; }
    __syncthreads();
  }
  if(t==0){
    float gs[4]={r0[0],r1[0],r2[0],r3[0]};
    float ld[4]={(float)cnt[0],(float)cnt[1],(float)cnt[2],(float)cnt[3]};
    float mu1=(gs[0]+gs[1]+gs[2]+gs[3])*0.25f;
    float v1=0.f; for(int i=0;i<4;i++){float d=gs[i]-mu1; v1+=d*d;} v1 *= (1.f/3.f);
    float mu2=(ld[0]+ld[1]+ld[2]+ld[3])*0.25f;
    float v2=0.f; for(int i=0;i<4;i++){float d=ld[i]-mu2; v2+=d*d;} v2 *= (1.f/3.f);
    lbl[0] = v1/(mu1*mu1+1e-10f) + v2/(mu2*mu2+1e-10f) + rl[0]*(1.f/2048.f);
  }
}

// ============ expert attention v3 (unchanged from round 8) ============
#define AT_LDS 149504

#define STAGE_QKV(hh_, ks_, dst_) do{ \
    _Pragma("unroll") \
    for(int _q=0;_q<3;_q++){ \
      unsigned _L = (unsigned)w*3072u + (unsigned)_q*1024u + (unsigned)lane*16u; \
      int _row = (int)(_L>>7); unsigned _pb = _L & 127u; \
      int _gc = (_row<64)? (hh_)*64+_row : (_row<128)? 512+(hh_)*64+(_row-64) : 1024+(hh_)*64+(_row-128); \
      const char* _g = Wq + (size_t)_gc*1024 + (ks_)*128 + (_pb ^ ((unsigned)(_row&7)<<4)); \
      gload16(_g, (dst_) + ((unsigned)w*3072u + (unsigned)_q*1024u)); \
    } }while(0)

#define STAGE_WO(hg_, s_, dst_) do{ \
    int _nh = (s_)>>2, _k2 = (s_)&3; \
    _Pragma("unroll") \
    for(int _q=0;_q<2;_q++){ \
      unsigned _L = (unsigned)w*2048u + (unsigned)_q*1024u + (unsigned)lane*16u; \
      int _row = (int)(_L>>7); unsigned _pb = _L & 127u; \
      const char* _g = WoP + (size_t)(_nh*128+_row)*1024 + (hg_)*512 + _k2*128 \
                     + (_pb ^ ((unsigned)(_row&7)<<4)); \
      gload16(_g, (dst_) + ((unsigned)w*2048u + (unsigned)_q*1024u)); \
    } }while(0)

__global__ __launch_bounds__(512,2) void k_expert_attn(
    const float* __restrict__ lat, const float* __restrict__ act,
    const unsigned short* __restrict__ Wqkv_t, const float* __restrict__ bqkv,
    const unsigned short* __restrict__ Wo_t,   const float* __restrict__ bo,
    const float* __restrict__ ln1g, const float* __restrict__ ln1b,
    const int* __restrict__ jobs, const int* __restrict__ cnt,
    unsigned short* __restrict__ x_bf){
  extern __shared__ char smem[];
  char* Abase = smem;                    // tokens, later XP (preLN)
  char* CTXb  = smem + 65536;            // [64] x 512B
  char* U     = smem + 98304;            // 48KB dbuf / QH union
  float* SC   = (float*)(smem + 147456); // [64][8]

  int bid = blockIdx.x;
  int e   = (bid&7)>>1;
  int blk = ((bid>>3)<<1) | (bid&1);
  int ne = cnt[e];
  int base = blk*8;
  if(base >= ne) return;
  int t = threadIdx.x;
  int w = t>>6, lane = t&63, lg = lane>>4, lm = lane&15;
  int mt = w>>1, wb = w&1;
  const int* jb = &jobs[e*2048 + base];

  #pragma unroll
  for(int i=0;i<8;i++){
    int u = i*512 + t; int row = u>>6, ch = u&63; int d0 = ch*8;
    int j = row>>3;
    int slot = (base + j < ne) ? jb[j] : jb[0];
    int b = slot>>1, n = row&7;
    const float* src = (d0<256)? &lat[((size_t)b*8+n)*256 + d0]
                               : &act[((size_t)b*8+n)*256 + (d0-256)];
    float4 f0 = *(const float4*)src; float4 f1 = *(const float4*)(src+4);
    bfpack8 pk;
    pk.u[0]=f2bf(f0.x); pk.u[1]=f2bf(f0.y); pk.u[2]=f2bf(f0.z); pk.u[3]=f2bf(f0.w);
    pk.u[4]=f2bf(f1.x); pk.u[5]=f2bf(f1.y); pk.u[6]=f2bf(f1.z); pk.u[7]=f2bf(f1.w);
    *(short8*)(Abase + (((unsigned)(row*1024 + ch*16)) ^ ((unsigned)(row&7)<<4))) = pk.v;
  }
  asm volatile("s_waitcnt lgkmcnt(0)" ::: "memory");

  const char* Wq  = (const char*)(Wqkv_t + (size_t)e*1536*512);
  const char* WoP = (const char*)(Wo_t   + (size_t)e*512*512);
  unsigned short* QH = (unsigned short*)U;

  f32x4 acc2[4][4];
  #pragma unroll
  for(int a=0;a<4;a++)
    #pragma unroll
    for(int b2=0;b2<4;b2++) acc2[a][b2]=(f32x4){0.f,0.f,0.f,0.f};

  for(int hg=0; hg<2; hg++){
    for(int hh=0; hh<4; hh++){
      int h = hg*4 + hh;
      f32x4 acc1[6];
      #pragma unroll
      for(int i=0;i<6;i++) acc1[i]=(f32x4){0.f,0.f,0.f,0.f};

      STAGE_QKV(h, 0, U);
      #pragma unroll
      for(int ks=0; ks<8; ks++){
        char* nxt = U + (((ks+1)&1) ? 24576u : 0u);
        if(ks<7) STAGE_QKV(h, ks+1, nxt);
        if(ks<7) asm volatile("s_waitcnt vmcnt(3)" ::: "memory");
        else     asm volatile("s_waitcnt vmcnt(0)" ::: "memory");
        FBAR();
        const char* bs = U + ((ks&1) ? 24576u : 0u);
        int arow = mt*16+lm;
        #pragma unroll
        for(int half=0; half<2; half++){
          short8 a = *(const short8*)(Abase + (unsigned)arow*1024u
                       + (((unsigned)(ks*128 + half*64 + lg*16)) ^ ((unsigned)(arow&7)<<4)));
          #pragma unroll
          for(int i=0;i<6;i++){
            int brow = (wb*6+i)*16+lm;
            short8 bb = *(const short8*)(bs + (unsigned)brow*128u
                         + (((unsigned)(half*64+lg*16)) ^ ((unsigned)(brow&7)<<4)));
            acc1[i] = MFMA_BF16(a, bb, acc1[i]);
          }
        }
        FBAR();
      }
      #pragma unroll
      for(int i=0;i<6;i++){
        int L = (wb*6+i)*16 + lm;
        int gc = (L<64)? h*64+L : (L<128)? 512+h*64+(L-64) : 1024+h*64+(L-128);
        float bia = bqkv[e*1536 + gc];
        #pragma unroll
        for(int rr=0;rr<4;rr++){
          int row = mt*16 + lg*4 + rr;
          QH[row*200 + L] = f2bf(acc1[i][rr] + bia);
        }
      }
      __syncthreads();
      {
        int r = t>>3, p = t&7, j = r>>3;
        float s = 0.f;
        #pragma unroll
        for(int dd=0; dd<64; dd+=8){
          bfpack8 qa; qa.v = *(const short8*)&QH[r*200 + dd];
          bfpack8 ka; ka.v = *(const short8*)&QH[(j*8+p)*200 + 64 + dd];
          #pragma unroll
          for(int ii=0;ii<8;ii++) s += bf2f(qa.u[ii])*bf2f(ka.u[ii]);
        }
        SC[r*8+p] = s * 0.125f;
      }
      __syncthreads();
      {
        int r = t>>3, p = t&7, j = r>>3;
        float sv[8]; float m = -1e30f;
        #pragma unroll
        for(int kk=0;kk<8;kk++){ sv[kk]=SC[r*8+kk]; m = fmaxf(m, sv[kk]); }
        float ssum = 0.f;
        #pragma unroll
        for(int kk=0;kk<8;kk++){ sv[kk]=__expf(sv[kk]-m); ssum += sv[kk]; }
        float inv = 1.f/ssum;
        float o[8] = {0.f,0.f,0.f,0.f,0.f,0.f,0.f,0.f};
        #pragma unroll
        for(int kk=0;kk<8;kk++){
          float pr = sv[kk]*inv;
          bfpack8 va; va.v = *(const short8*)&QH[(j*8+kk)*200 + 128 + p*8];
          #pragma unroll
          for(int ii=0;ii<8;ii++) o[ii] += pr * bf2f(va.u[ii]);
        }
        bfpack8 pk;
        #pragma unroll
        for(int ii=0;ii<8;ii++) pk.u[ii]=f2bf(o[ii]);
        *(short8*)(CTXb + (((unsigned)(r*512 + hh*128 + p*16)) ^ ((unsigned)(r&7)<<4))) = pk.v;
      }
      __syncthreads();
    }

    STAGE_WO(hg, 0, U);
    #pragma unroll
    for(int s=0; s<16; s++){
      int nh = s>>2, k2 = s&3;
      char* nxt = U + (((s+1)&1) ? 16384u : 0u);
      if(s<15) STAGE_WO(hg, s+1, nxt);
      if(s<15) asm volatile("s_waitcnt vmcnt(2)" ::: "memory");
      else     asm volatile("s_waitcnt vmcnt(0)" ::: "memory");
      FBAR();
      const char* bs = U + ((s&1) ? 16384u : 0u);
      int arow = mt*16+lm;
      #pragma unroll
      for(int half=0; half<2; half++){
        short8 a = *(const short8*)(CTXb + (unsigned)arow*512u
                     + (((unsigned)(k2*128 + half*64 + lg*16)) ^ ((unsigned)(arow&7)<<4)));
        #pragma unroll
        for(int i=0;i<4;i++){
          int brow = (wb*4+i)*16+lm;
          short8 bb = *(const short8*)(bs + (unsigned)brow*128u
                       + (((unsigned)(half*64+lg*16)) ^ ((unsigned)(brow&7)<<4)));
          acc2[nh][i] = MFMA_BF16(a, bb, acc2[nh][i]);
        }
      }
      FBAR();
    }
  }

  #pragma unroll
  for(int nh=0; nh<4; nh++)
    #pragma unroll
    for(int i=0;i<4;i++){
      int gcol = nh*128 + (wb*4+i)*16 + lm;
      float bia = bo[e*512 + gcol];
      #pragma unroll
      for(int rr=0;rr<4;rr++){
        int row = mt*16 + lg*4 + rr;
        int j2 = row>>3;
        int slot = (base+j2<ne)? jb[j2] : jb[0];
        int b = slot>>1, n = row&7;
        float tok = (gcol<256)? lat[((size_t)b*8+n)*256 + gcol]
                              : act[((size_t)b*8+n)*256 + gcol - 256];
        *(unsigned short*)(Abase + (((unsigned)(row*1024 + gcol*2)) ^ ((unsigned)(row&7)<<4)))
            = f2bf(acc2[nh][i][rr] + bia + tok);
      }
    }
  __syncthreads();
  {
    int r = t>>3, p = t&7;
    unsigned rsw = ((unsigned)(r&7))<<4;
    bfpack8 xv[8];
    float sum=0.f, sq=0.f;
    #pragma unroll
    for(int j=0;j<8;j++){
      xv[j].v = *(const short8*)(Abase + (((unsigned)(r*1024 + j*128 + p*16)) ^ rsw));
      #pragma unroll
      for(int ii=0;ii<8;ii++){ float f = bf2f(xv[j].u[ii]); sum += f; sq += f*f; }
    }
    sum += __shfl_xor(sum,1); sq += __shfl_xor(sq,1);
    sum += __shfl_xor(sum,2); sq += __shfl_xor(sq,2);
    sum += __shfl_xor(sum,4); sq += __shfl_xor(sq,4);
    float mu = sum*(1.f/512.f);
    float var = sq*(1.f/512.f) - mu*mu;
    float rstd = rsqrtf(var + LN_EPS);
    int j8 = r>>3;
    if(base + j8 < ne){
      int slot = jb[j8]; int n = r&7;
      unsigned short* dst = &x_bf[((size_t)slot*8+n)*512];
      #pragma unroll
      for(int j=0;j<8;j++){
        bfpack8 pk;
        #pragma unroll
        for(int ii=0;ii<8;ii++){
          int gc = j*64 + p*8 + ii;
          float xvv = (bf2f(xv[j].u[ii]) - mu)*rstd*ln1g[e*512+gc] + ln1b[e*512+gc];
          pk.u[ii] = f2bf(xvv);
        }
        *(short8*)&dst[j*64 + p*8] = pk.v;
      }
    }
  }
}

// ============ expert FFN v5: 128-col chunks, 66.5KB LDS -> 2 blocks/CU ============
// 512 thr, 8 waves 2m x 4n; wave tile 32 rows x 32 cols (ns=2).
// LDS: BS dbuf 2x16KB @0, HC [64][136] bf16 @32768 (17408B). PL [64][520] overlays all (66560B).
#define E2_LDS 66560
#define E2_HP  136

#define FFN_STAGE_W1(cc, kk, dst) do{ \
    unsigned _Lw = (unsigned)w*2048u; \
    _Pragma("unroll") \
    for(int _q=0;_q<2;_q++){ \
      unsigned _L = _Lw + (unsigned)_q*1024u + (unsigned)lane*16u; \
      int _row = (int)(_L>>7); unsigned _pb = _L&127u; \
      const char* _g = W1 + (size_t)((cc)*128+_row)*1024 + (kk)*128 + (_pb ^ ((unsigned)(_row&7)<<4)); \
      gload16(_g, (dst) + (_Lw + (unsigned)_q*1024u)); \
    } }while(0)

#define FFN_STAGE_W2(cc, nn, kk, dst) do{ \
    unsigned _Lw = (unsigned)w*2048u; \
    _Pragma("unroll") \
    for(int _q=0;_q<2;_q++){ \
      unsigned _L = _Lw + (unsigned)_q*1024u + (unsigned)lane*16u; \
      int _row = (int)(_L>>7); unsigned _pb = _L&127u; \
      const char* _g = W2 + (size_t)((nn)*128+_row)*4096 + ((cc)*128+(kk)*64)*2 \
                     + (_pb ^ ((unsigned)(_row&7)<<4)); \
      gload16(_g, (dst) + (_Lw + (unsigned)_q*1024u)); \
    } }while(0)

__global__ __launch_bounds__(512,4) void k_expert_ffn(
    const unsigned short* __restrict__ x_bf,
    const unsigned short* __restrict__ Wf1_t, const float* __restrict__ bf1,
    const unsigned short* __restrict__ Wf2_t, const float* __restrict__ bf2v,
    const float* __restrict__ ln2g, const float* __restrict__ ln2b,
    const int* __restrict__ jobs, const int* __restrict__ cnt,
    unsigned short* __restrict__ slot_out){
  extern __shared__ char smem[];
  char* BSB0 = smem;
  char* BSB1 = smem + 16384;
  unsigned short* HC = (unsigned short*)(smem + 32768);
  unsigned short* PL = (unsigned short*)smem;   // overlay after K-loops

  // balanced XCD map: XCD pair (2e,2e+1) owns expert e
  int bid = blockIdx.x;
  int e   = (bid&7)>>1;
  int blk = ((bid>>3)<<1) | (bid&1);
  int ne = cnt[e];
  int base = blk*8;
  if(base >= ne) return;
  int t = threadIdx.x;
  int w = t>>6, lane = t&63, lg = lane>>4, lm = lane&15;
  int mg = w>>2, ng = w&3;                    // 2m x 4n wave grid
  const int* jb = &jobs[e*2048 + base];
  unsigned bswz = ((unsigned)(lm&7))<<4;      // B-read swizzle (brow&7 == lm&7)

  const char* W1 = (const char*)(Wf1_t + (size_t)e*2048*512);
  const char* W2 = (const char*)(Wf2_t + (size_t)e*512*2048);

  // per-lane x base addresses for A-frags (row = mg*32 + ms*16 + lm)
  const char* xb[2];
  #pragma unroll
  for(int ms=0;ms<2;ms++){
    int row = mg*32 + ms*16 + lm;
    int j = row>>3;
    int slot = (base+j<ne)? jb[j] : jb[0];
    int n = row&7;
    xb[ms] = (const char*)x_bf + (((size_t)slot*8+n)<<10) + (size_t)(lg*16);
  }

  // x-frag double buffer: xf[parity][ms][half]
  short8 xf[2][2][2];
  #pragma unroll
  for(int ms=0;ms<2;ms++)
    #pragma unroll
    for(int hf=0;hf<2;hf++)
      xf[0][ms][hf] = *(const short8*)(xb[ms] + hf*64);

  f32x4 acc[4][2][2];   // [nh][ms][ns] persistent G2 accumulator (64 VGPR)
  #pragma unroll
  for(int a=0;a<4;a++)
    #pragma unroll
    for(int b=0;b<2;b++)
      #pragma unroll
      for(int c2=0;c2<2;c2++) acc[a][b][c2]=(f32x4){0.f,0.f,0.f,0.f};

  // prologue
  FFN_STAGE_W1(0, 0, BSB0);

  for(int c=0; c<16; c++){
    f32x4 acc1[2][2];
    #pragma unroll
    for(int b=0;b<2;b++)
      #pragma unroll
      for(int c2=0;c2<2;c2++) acc1[b][c2]=(f32x4){0.f,0.f,0.f,0.f};

    // ---- G1: h_c[64][128] = x @ W1[:, c*128..+128], 8 k-steps
    #pragma unroll
    for(int ks=0; ks<8; ks++){
      // x-frag prefetch FIRST (older than stage -> reg-dep wait stays loose)
      #pragma unroll
      for(int ms=0;ms<2;ms++)
        #pragma unroll
        for(int hf=0;hf<2;hf++)
          xf[(ks+1)&1][ms][hf] = *(const short8*)(xb[ms] + (((ks+1)&7)*128 + hf*64));
      char* nxt = ((ks+1)&1) ? BSB1 : BSB0;
      if(ks<7) FFN_STAGE_W1(c, ks+1, nxt);
      else     FFN_STAGE_W2(c, 0, 0, nxt);
      asm volatile("s_waitcnt vmcnt(6)" ::: "memory");
      FBAR();
      const char* bs = (ks&1) ? BSB1 : BSB0;
      #pragma unroll
      for(int hf=0;hf<2;hf++){
        #pragma unroll
        for(int ns=0;ns<2;ns++){
          unsigned boff = (unsigned)((ng*32+ns*16+lm)*128);
          short8 bb = *(const short8*)(bs + boff + (((unsigned)(hf*64+lg*16)) ^ bswz));
          acc1[0][ns] = MFMA_BF16(xf[ks&1][0][hf], bb, acc1[0][ns]);
          acc1[1][ns] = MFMA_BF16(xf[ks&1][1][hf], bb, acc1[1][ns]);
        }
      }
      if(ks==7){
        #pragma unroll
        for(int ms=0;ms<2;ms++)
          #pragma unroll
          for(int ns=0;ns<2;ns++){
            int colL = ng*32 + ns*16 + lm;
            float bia = bf1[e*2048 + c*128 + colL];
            #pragma unroll
            for(int rr=0;rr<4;rr++){
              int row = mg*32 + ms*16 + lg*4 + rr;
              HC[row*E2_HP + colL] = f2bf(fmaxf(acc1[ms][ns][rr] + bia, 0.f));
            }
          }
        asm volatile("s_waitcnt lgkmcnt(0)" ::: "memory");
      }
      FBAR();
    }

    // ---- G2: acc += h_c @ W2[c-chunk k, :]; 8 steps (nh 0..3 x k2 0..1)
    #pragma unroll
    for(int s2=0; s2<8; s2++){
      const int nh = s2>>1, k2 = s2&1;
      char* nxt = ((s2+1)&1) ? BSB1 : BSB0;
      if(s2<7)       FFN_STAGE_W2(c, (s2+1)>>1, (s2+1)&1, nxt);
      else if(c<15)  FFN_STAGE_W1(c+1, 0, nxt);
      if(s2<7 || c<15) asm volatile("s_waitcnt vmcnt(2)" ::: "memory");
      else             asm volatile("s_waitcnt vmcnt(0)" ::: "memory");
      FBAR();
      const char* bs = (s2&1) ? BSB1 : BSB0;
      #pragma unroll
      for(int hf=0;hf<2;hf++){
        short8 ha0 = *(const short8*)&HC[(mg*32 +      lm)*E2_HP + k2*64 + hf*32 + lg*8];
        short8 ha1 = *(const short8*)&HC[(mg*32 + 16 + lm)*E2_HP + k2*64 + hf*32 + lg*8];
        #pragma unroll
        for(int ns=0;ns<2;ns++){
          unsigned boff = (unsigned)((ng*32+ns*16+lm)*128);
          short8 bb = *(const short8*)(bs + boff + (((unsigned)(hf*64+lg*16)) ^ bswz));
          acc[nh][0][ns] = MFMA_BF16(ha0, bb, acc[nh][0][ns]);
          acc[nh][1][ns] = MFMA_BF16(ha1, bb, acc[nh][1][ns]);
        }
      }
      FBAR();
    }
  }

  // ---- PL = acc + bf2 (residual added in LN phase from global) ----
  #pragma unroll
  for(int nh=0;nh<4;nh++)
    #pragma unroll
    for(int ms=0;ms<2;ms++)
      #pragma unroll
      for(int ns=0;ns<2;ns++){
        int col = nh*128 + ng*32 + ns*16 + lm;
        float bia = bf2v[e*512+col];
        #pragma unroll
        for(int rr=0;rr<4;rr++){
          int row = mg*32 + ms*16 + lg*4 + rr;
          PL[row*520 + col] = f2bf(acc[nh][ms][ns][rr] + bia);
        }
      }
  __syncthreads();

  // ---- LN2 (+global residual) -> slot_out ----
  {
    int r = t>>3, p = t&7;
    int j8 = r>>3;
    int slot = (base + j8 < ne) ? jb[j8] : jb[0];
    int n = r&7;
    const unsigned short* xg = &x_bf[((size_t)slot*8+n)*512];
    bfpack8 cv[8];
    float sum=0.f, sq=0.f;
    #pragma unroll
    for(int j=0;j<8;j++){
      bfpack8 pa; pa.v = *(const short8*)&PL[r*520 + j*64 + p*8];
      bfpack8 xa; xa.v = *(const short8*)&xg[j*64 + p*8];
      #pragma unroll
      for(int ii=0;ii<8;ii++){
        float f = bf2f(pa.u[ii]) + bf2f(xa.u[ii]);
        cv[j].u[ii] = f2bf(f);
        f = bf2f(cv[j].u[ii]);
        sum += f; sq += f*f;
      }
    }
    sum += __shfl_xor(sum,1); sq += __shfl_xor(sq,1);
    sum += __shfl_xor(sum,2); sq += __shfl_xor(sq,2);
    sum += __shfl_xor(sum,4); sq += __shfl_xor(sq,4);
    float mu = sum*(1.f/512.f);
    float var = sq*(1.f/512.f) - mu*mu;
    float rstd = rsqrtf(var + LN_EPS);
    if(base + j8 < ne){
      unsigned short* dst = &slot_out[((size_t)slot*8+n)*512];
      #pragma unroll
      for(int j=0;j<8;j++){
        bfpack8 pk;
        #pragma unroll
        for(int ii=0;ii<8;ii++){
          int gc = j*64 + p*8 + ii;
          float xv = (bf2f(cv[j].u[ii]) - mu)*rstd*ln2g[e*512+gc] + ln2b[e*512+gc];
          pk.u[ii] = f2bf(xv);
        }
        *(short8*)&dst[j*64 + p*8] = pk.v;
      }
    }
  }
}

// ============ combine: mixed_bf[b][d] = w0*out[2b][d] + w1*out[2b+1][d] ============
__global__ __launch_bounds__(256) void k_combine(const unsigned short* __restrict__ so,
    const float* __restrict__ slotw, unsigned short* __restrict__ mx){
  int gid = blockIdx.x*256 + threadIdx.x;
  int b = gid >> 9, c8 = gid & 511;
  float w0 = slotw[b*2+0], w1 = slotw[b*2+1];
  bfpack8 x0; x0.v = *(const short8*)&so[((size_t)(b*2+0))*4096 + c8*8];
  bfpack8 x1; x1.v = *(const short8*)&so[((size_t)(b*2+1))*4096 + c8*8];
  bfpack8 o;
  #pragma unroll
  for(int j=0;j<8;j++) o.u[j] = f2bf(w0*bf2f(x0.u[j]) + w1*bf2f(x1.u[j]));
  *(short8*)&mx[(size_t)b*4096 + c8*8] = o.v;
}

// ============ head GEMM 1: hidden = relu(mixed_bf @ hW1 + b1) ============
#define H_SP 72
__global__ __launch_bounds__(256) void k_head1(const unsigned short* __restrict__ mixbf,
    const unsigned short* __restrict__ hW1t, const float* __restrict__ b1,
    unsigned short* __restrict__ hidden){
  __shared__ unsigned short As[64*H_SP], Bs[64*H_SP];
  int n0 = blockIdx.x*64, m0 = blockIdx.y*64;
  int t = threadIdx.x, w = t>>6, lane = t&63, lg = lane>>4, lm = lane&15;
  f32x4 acc[4]; for(int i=0;i<4;i++) acc[i]=(f32x4){0.f,0.f,0.f,0.f};
  for(int ks=0; ks<64; ks++){
    __syncthreads();
    int k0 = ks*64;
    for(int i=0;i<2;i++){
      int u = i*256 + t; int row = u>>3, ch = u&7;
      *(short8*)&As[row*H_SP + ch*8] = *(const short8*)&mixbf[(size_t)(m0+row)*4096 + k0 + ch*8];
    }
    for(int i=0;i<2;i++){
      int u = i*256 + t; int row = u>>3, ch = u&7;
      *(short8*)&Bs[row*H_SP + ch*8] = *(const short8*)&hW1t[(size_t)(n0+row)*4096 + k0 + ch*8];
    }
    __syncthreads();
    for(int half=0; half<2; half++){
      short8 a = *(const short8*)&As[(w*16+lm)*H_SP + half*32 + lg*8];
      for(int i=0;i<4;i++){
        short8 bb = *(const short8*)&Bs[(i*16+lm)*H_SP + half*32 + lg*8];
        acc[i] = MFMA_BF16(a, bb, acc[i]);
      }
    }
  }
  for(int i=0;i<4;i++){
    int gc = n0 + i*16 + lm; float bia = b1[gc];
    for(int rr=0; rr<4; rr++){
      int row = m0 + w*16 + lg*4 + rr;
      hidden[(size_t)row*512 + gc] = f2bf(fmaxf(acc[i][rr] + bia, 0.f));
    }
  }
}

// ============ head GEMM 2: logits = hidden @ hW2 + b2 ============
__global__ __launch_bounds__(256) void k_head2(const unsigned short* __restrict__ hidden,
    const unsigned short* __restrict__ hW2t, const float* __restrict__ b2,
    float* __restrict__ out){
  __shared__ unsigned short As[64*H_SP], Bs[112*H_SP];
  int m0 = blockIdx.x*64;
  int t = threadIdx.x, w = t>>6, lane = t&63, lg = lane>>4, lm = lane&15;
  f32x4 acc[7]; for(int i=0;i<7;i++) acc[i]=(f32x4){0.f,0.f,0.f,0.f};
  for(int ks=0; ks<8; ks++){
    __syncthreads();
    int k0 = ks*64;
    for(int i=0;i<2;i++){
      int u = i*256 + t; int row = u>>3, ch = u&7;
      *(short8*)&As[row*H_SP + ch*8] = *(const short8*)&hidden[(size_t)(m0+row)*512 + k0 + ch*8];
    }
    for(int i=0;i<4;i++){
      int u = i*256 + t;
      if(u < 896){
        int row = u>>3, ch = u&7;
        *(short8*)&Bs[row*H_SP + ch*8] = *(const short8*)&hW2t[(size_t)row*512 + k0 + ch*8];
      }
    }
    __syncthreads();
    for(int half=0; half<2; half++){
      short8 a = *(const short8*)&As[(w*16+lm)*H_SP + half*32 + lg*8];
      for(int i=0;i<7;i++){
        short8 bb = *(const short8*)&Bs[(i*16+lm)*H_SP + half*32 + lg*8];
        acc[i] = MFMA_BF16(a, bb, acc[i]);
      }
    }
  }
  for(int i=0;i<7;i++){
    int col = i*16 + lm;
    if(col < 101){
      float bia = b2[col];
      for(int rr=0; rr<4; rr++){
        int row = m0 + w*16 + lg*4 + rr;
        out[(size_t)row*101 + col] = acc[i][rr] + bia;
      }
    }
  }
}

// ================= host launcher =================
extern "C" void kernel_launch(void* const* d_in, const int* in_sizes, int n_in,
                              void* d_out, int out_size, void* d_ws, size_t ws_size,
                              hipStream_t stream){
  if(ws_size < WS_NEED) return;
  const float* lat  = (const float*)d_in[0];
  const float* act  = (const float*)d_in[1];
  const float* gateW= (const float*)d_in[2];
  const float* Wqkv = (const float*)d_in[3];
  const float* bqkv = (const float*)d_in[4];
  const float* Wo   = (const float*)d_in[5];
  const float* bo   = (const float*)d_in[6];
  const float* ln1g = (const float*)d_in[7];
  const float* ln1b = (const float*)d_in[8];
  const float* Wf1  = (const float*)d_in[9];
  const float* bf1  = (const float*)d_in[10];
  const float* Wf2  = (const float*)d_in[11];
  const float* bf2v = (const float*)d_in[12];
  const float* ln2g = (const float*)d_in[13];
  const float* ln2b = (const float*)d_in[14];
  const float* hW1  = (const float*)d_in[15];
  const float* hb1  = (const float*)d_in[16];
  const float* hW2  = (const float*)d_in[17];
  const float* hb2  = (const float*)d_in[18];
  float* out = (float*)d_out;
  char* ws = (char*)d_ws;

  unsigned short* WQKVT = (unsigned short*)(ws + OFF_WQKVT);
  unsigned short* WOT   = (unsigned short*)(ws + OFF_WOT);
  unsigned short* WF1T  = (unsigned short*)(ws + OFF_WF1T);
  unsigned short* WF2T  = (unsigned short*)(ws + OFF_WF2T);
  unsigned short* HW1T  = (unsigned short*)(ws + OFF_HW1T);
  unsigned short* HW2T  = (unsigned short*)(ws + OFF_HW2T);
  unsigned short* XBF   = (unsigned short*)(ws + OFF_XBF);   // x after LN1; reused as MIXEDBF
  unsigned short* SLOTO = (unsigned short*)(ws + OFF_SLOTO);
  unsigned short* MIXBF = XBF;
  unsigned short* HID = (unsigned short*)(ws + OFF_HID);
  int* JOBS = (int*)(ws + OFF_JOBS);
  float* SLOTW = (float*)(ws + OFF_SLOTW);
  float* LSE = (float*)(ws + OFF_LSE);
  int* CNT = (int*)(ws + OFF_CNT);

  (void)hipFuncSetAttribute((const void*)k_expert_attn,
      hipFuncAttributeMaxDynamicSharedMemorySize, AT_LDS);
  (void)hipFuncSetAttribute((const void*)k_expert_ffn,
      hipFuncAttributeMaxDynamicSharedMemorySize, E2_LDS);

  hipMemsetAsync(CNT, 0, 16, stream);
  hipMemsetAsync(HW2T, 0, 112*512*2, stream);

  // weight transposes (fp32 -> bf16, [R][C] -> [C][R])
  k_transpose_cast<<<dim3(48,16,4),256,0,stream>>>(Wqkv, WQKVT, 512, 1536);
  k_transpose_cast<<<dim3(16,16,4),256,0,stream>>>(Wo,   WOT,   512, 512);
  k_transpose_cast<<<dim3(64,16,4),256,0,stream>>>(Wf1,  WF1T,  512, 2048);
  k_transpose_cast<<<dim3(16,64,4),256,0,stream>>>(Wf2,  WF2T,  2048, 512);
  k_transpose_cast<<<dim3(16,128,1),256,0,stream>>>(hW1, HW1T,  4096, 512);
  k_transpose_cast<<<dim3(4,16,1),256,0,stream>>>(hW2,  HW2T,  512, 101);

  k_router<<<2048,256,0,stream>>>(lat, act, gateW, out + OUT_GATES, JOBS, CNT, SLOTW, LSE);
  k_finalize<<<1,256,0,stream>>>(out + OUT_GATES, LSE, CNT, out + OUT_LBL);

  k_expert_attn<<<1024, 512, AT_LDS, stream>>>(lat, act, WQKVT, bqkv, WOT, bo,
      ln1g, ln1b, JOBS, CNT, XBF);
  k_expert_ffn<<<1024, 512, E2_LDS, stream>>>(XBF, WF1T, bf1, WF2T, bf2v,
      ln2g, ln2b, JOBS, CNT, SLOTO);
  k_combine<<<4096,256,0,stream>>>(SLOTO, SLOTW, MIXBF);

  k_head1<<<dim3(8,32),256,0,stream>>>(MIXBF, HW1T, hb1, HID);
  k_head2<<<32,256,0,stream>>>(HID, HW2T, hb2, out);
}

// Round 10
// 981.784 us; speedup vs baseline: 1.0953x; 1.0953x over previous
//
#include <hip/hip_runtime.h>
#include <stdint.h>

// ---------------- problem constants ----------------
#define NB    2048
#define NAG   8
#define NEXP  4
#define LN_EPS 1e-5f

#define OUT_GATES  (2048*101)            // 206848
#define OUT_LBL    (OUT_GATES + 2048*4)  // 215040

typedef __attribute__((ext_vector_type(8))) short short8;
typedef __attribute__((ext_vector_type(4))) float f32x4;

#define MFMA_BF16(a,b,c) __builtin_amdgcn_mfma_f32_16x16x32_bf16((a),(b),(c),0,0,0)

__device__ __forceinline__ float bf2f(unsigned short h){
  union { unsigned int u; float f; } v; v.u = ((unsigned int)h) << 16; return v.f;
}
__device__ __forceinline__ unsigned short f2bf(float x){
  union { float f; unsigned int u; } v; v.f = x;
  unsigned int r = v.u + 0x7FFFu + ((v.u >> 16) & 1u);
  return (unsigned short)(r >> 16);
}
union bfpack8 { short8 v; unsigned short u[8]; };

// async global->LDS DMA, 16B per lane; LDS dest = wave-uniform base + lane*16
__device__ __forceinline__ void gload16(const void* g, void* l){
  __builtin_amdgcn_global_load_lds(
      (const __attribute__((address_space(1))) void*)g,
      (__attribute__((address_space(3))) void*)l, 16, 0, 0);
}

// raw barrier with compiler memory fences (no vmcnt drain!)
#define FBAR() do{ asm volatile("" ::: "memory"); \
                   __builtin_amdgcn_s_barrier(); \
                   asm volatile("" ::: "memory"); }while(0)

// ---------------- workspace layout (bytes) ----------------
#define OFF_WQKVT  0ULL                      // [4][1536][512] bf16
#define OFF_WOT    6291456ULL                // [4][512][512]
#define OFF_WF1T   8388608ULL                // [4][2048][512]
#define OFF_WF2T   16777216ULL               // [4][512][2048]
#define OFF_HW1T   25165824ULL               // [512][4096]
#define OFF_HW2T   29360128ULL               // [112][512] (zero-padded rows)
#define OFF_XBF    29474816ULL               // [4096][8][512] bf16 (x after LN1); MIXEDBF overlays after FFN
#define OFF_SLOTO  63029248ULL               // [4096][4096] bf16 per-slot LN2 out
#define OFF_HID    96583680ULL               // [2048][512] bf16
#define OFF_JOBS   98680832ULL               // int[4][2048] slot ids (slot=b*2+s)
#define OFF_SLOTW  98713600ULL               // float[4096] gate weight per slot
#define OFF_LSE    98729984ULL               // float[2048]
#define OFF_CNT    98738176ULL               // int[4]
#define WS_NEED    98738192ULL

// ============ transpose+cast: src f32 [E][R][C] -> dst bf16 [E][C][R] ============
__global__ __launch_bounds__(256) void k_transpose_cast(const float* __restrict__ src,
    unsigned short* __restrict__ dst, int R, int C){
  __shared__ float tile[32][33];
  int e = blockIdx.z;
  int c0 = blockIdx.x*32, r0 = blockIdx.y*32;
  const float* s = src + (size_t)e*R*C;
  unsigned short* d = dst + (size_t)e*C*R;
  int tx = threadIdx.x & 31, ty = threadIdx.x >> 5;
  for(int yy = ty; yy < 32; yy += 8){
    int r = r0+yy, c = c0+tx;
    if(r<R && c<C) tile[yy][tx] = s[(size_t)r*C + c];
  }
  __syncthreads();
  for(int yy = ty; yy < 32; yy += 8){
    int oc = c0+yy, orr = r0+tx;
    if(oc<C && orr<R) d[(size_t)oc*R + orr] = f2bf(tile[tx][yy]);
  }
}

// ============ router: logits, top2 gates, job lists, lse ============
__global__ __launch_bounds__(256) void k_router(const float* __restrict__ lat,
    const float* __restrict__ act, const float* __restrict__ gateW,
    float* __restrict__ gates_out, int* __restrict__ jobs, int* __restrict__ cnt,
    float* __restrict__ slot_w, float* __restrict__ lse_arr){
  int b = blockIdx.x, t = threadIdx.x;
  float a0=0.f,a1=0.f,a2=0.f,a3=0.f;
  for(int i=t;i<4096;i+=256){
    int n=i>>9, d=i&511;
    float v = (d<256)? lat[((size_t)b*8+n)*256 + d] : act[((size_t)b*8+n)*256 + (d-256)];
    float4 gw = *(const float4*)&gateW[(size_t)i*4];
    a0 += v*gw.x; a1 += v*gw.y; a2 += v*gw.z; a3 += v*gw.w;
  }
  __shared__ float red[4][256];
  red[0][t]=a0; red[1][t]=a1; red[2][t]=a2; red[3][t]=a3;
  __syncthreads();
  for(int s=128;s>0;s>>=1){
    if(t<s){ red[0][t]+=red[0][t+s]; red[1][t]+=red[1][t+s]; red[2][t]+=red[2][t+s]; red[3][t]+=red[3][t+s]; }
    __syncthreads();
  }
  if(t==0){
    float lg[4] = {red[0][0], red[1][0], red[2][0], red[3][0]};
    int i1=0; for(int e=1;e<4;e++) if(lg[e]>lg[i1]) i1=e;
    int i2=-1; for(int e=0;e<4;e++){ if(e==i1) continue; if(i2<0 || lg[e]>lg[i2]) i2=e; }
    float m = lg[i1];
    float e2 = __expf(lg[i2]-m);
    float inv = 1.f/(1.f+e2);
    float w1 = inv, w2 = e2*inv;
    float g[4]={0.f,0.f,0.f,0.f}; g[i1]=w1; g[i2]=w2;
    gates_out[b*4+0]=g[0]; gates_out[b*4+1]=g[1]; gates_out[b*4+2]=g[2]; gates_out[b*4+3]=g[3];
    float s=0.f; for(int e=0;e<4;e++) s += __expf(lg[e]-m);
    lse_arr[b] = m + __logf(s);
    int p1 = atomicAdd(&cnt[i1],1); jobs[i1*2048+p1] = b*2+0; slot_w[b*2+0] = w1;
    int p2 = atomicAdd(&cnt[i2],1); jobs[i2*2048+p2] = b*2+1; slot_w[b*2+1] = w2;
  }
}

// ============ finalize: load-balance loss ============
__global__ __launch_bounds__(256) void k_finalize(const float* __restrict__ gates,
    const float* __restrict__ lse_arr, const int* __restrict__ cnt, float* __restrict__ lbl){
  __shared__ float r0[256], r1[256], r2[256], r3[256], rl[256];
  int t = threadIdx.x;
  float g0=0.f,g1=0.f,g2=0.f,g3=0.f,l=0.f;
  for(int b=t;b<2048;b+=256){
    g0+=gates[b*4+0]; g1+=gates[b*4+1]; g2+=gates[b*4+2]; g3+=gates[b*4+3];
    l += lse_arr[b];
  }
  r0[t]=g0;r1[t]=g1;r2[t]=g2;r3[t]=g3;rl[t]=l;
  __syncthreads();
  for(int s=128;s>0;s>>=1){
    if(t<s){ r0[t]+=r0[t+s]; r1[t]+=r1[t+s]; r2[t]+=r2[t+s]; r3[t]+=r3[t+s]; rl[t]+=rl[t+s]; }
    __syncthreads();
  }
  if(t==0){
    float gs[4]={r0[0],r1[0],r2[0],r3[0]};
    float ld[4]={(float)cnt[0],(float)cnt[1],(float)cnt[2],(float)cnt[3]};
    float mu1=(gs[0]+gs[1]+gs[2]+gs[3])*0.25f;
    float v1=0.f; for(int i=0;i<4;i++){float d=gs[i]-mu1; v1+=d*d;} v1 *= (1.f/3.f);
    float mu2=(ld[0]+ld[1]+ld[2]+ld[3])*0.25f;
    float v2=0.f; for(int i=0;i<4;i++){float d=ld[i]-mu2; v2+=d*d;} v2 *= (1.f/3.f);
    lbl[0] = v1/(mu1*mu1+1e-10f) + v2/(mu2*mu2+1e-10f) + rl[0]*(1.f/2048.f);
  }
}

// ============ expert attention v3 (unchanged) ============
#define AT_LDS 149504

#define STAGE_QKV(hh_, ks_, dst_) do{ \
    _Pragma("unroll") \
    for(int _q=0;_q<3;_q++){ \
      unsigned _L = (unsigned)w*3072u + (unsigned)_q*1024u + (unsigned)lane*16u; \
      int _row = (int)(_L>>7); unsigned _pb = _L & 127u; \
      int _gc = (_row<64)? (hh_)*64+_row : (_row<128)? 512+(hh_)*64+(_row-64) : 1024+(hh_)*64+(_row-128); \
      const char* _g = Wq + (size_t)_gc*1024 + (ks_)*128 + (_pb ^ ((unsigned)(_row&7)<<4)); \
      gload16(_g, (dst_) + ((unsigned)w*3072u + (unsigned)_q*1024u)); \
    } }while(0)

#define STAGE_WO(hg_, s_, dst_) do{ \
    int _nh = (s_)>>2, _k2 = (s_)&3; \
    _Pragma("unroll") \
    for(int _q=0;_q<2;_q++){ \
      unsigned _L = (unsigned)w*2048u + (unsigned)_q*1024u + (unsigned)lane*16u; \
      int _row = (int)(_L>>7); unsigned _pb = _L & 127u; \
      const char* _g = WoP + (size_t)(_nh*128+_row)*1024 + (hg_)*512 + _k2*128 \
                     + (_pb ^ ((unsigned)(_row&7)<<4)); \
      gload16(_g, (dst_) + ((unsigned)w*2048u + (unsigned)_q*1024u)); \
    } }while(0)

__global__ __launch_bounds__(512,2) void k_expert_attn(
    const float* __restrict__ lat, const float* __restrict__ act,
    const unsigned short* __restrict__ Wqkv_t, const float* __restrict__ bqkv,
    const unsigned short* __restrict__ Wo_t,   const float* __restrict__ bo,
    const float* __restrict__ ln1g, const float* __restrict__ ln1b,
    const int* __restrict__ jobs, const int* __restrict__ cnt,
    unsigned short* __restrict__ x_bf){
  extern __shared__ char smem[];
  char* Abase = smem;                    // tokens, later XP (preLN)
  char* CTXb  = smem + 65536;            // [64] x 512B
  char* U     = smem + 98304;            // 48KB dbuf / QH union
  float* SC   = (float*)(smem + 147456); // [64][8]

  int bid = blockIdx.x;
  int e   = (bid&7)>>1;
  int blk = ((bid>>3)<<1) | (bid&1);
  int ne = cnt[e];
  int base = blk*8;
  if(base >= ne) return;
  int t = threadIdx.x;
  int w = t>>6, lane = t&63, lg = lane>>4, lm = lane&15;
  int mt = w>>1, wb = w&1;
  const int* jb = &jobs[e*2048 + base];

  #pragma unroll
  for(int i=0;i<8;i++){
    int u = i*512 + t; int row = u>>6, ch = u&63; int d0 = ch*8;
    int j = row>>3;
    int slot = (base + j < ne) ? jb[j] : jb[0];
    int b = slot>>1, n = row&7;
    const float* src = (d0<256)? &lat[((size_t)b*8+n)*256 + d0]
                               : &act[((size_t)b*8+n)*256 + (d0-256)];
    float4 f0 = *(const float4*)src; float4 f1 = *(const float4*)(src+4);
    bfpack8 pk;
    pk.u[0]=f2bf(f0.x); pk.u[1]=f2bf(f0.y); pk.u[2]=f2bf(f0.z); pk.u[3]=f2bf(f0.w);
    pk.u[4]=f2bf(f1.x); pk.u[5]=f2bf(f1.y); pk.u[6]=f2bf(f1.z); pk.u[7]=f2bf(f1.w);
    *(short8*)(Abase + (((unsigned)(row*1024 + ch*16)) ^ ((unsigned)(row&7)<<4))) = pk.v;
  }
  asm volatile("s_waitcnt lgkmcnt(0)" ::: "memory");

  const char* Wq  = (const char*)(Wqkv_t + (size_t)e*1536*512);
  const char* WoP = (const char*)(Wo_t   + (size_t)e*512*512);
  unsigned short* QH = (unsigned short*)U;

  f32x4 acc2[4][4];
  #pragma unroll
  for(int a=0;a<4;a++)
    #pragma unroll
    for(int b2=0;b2<4;b2++) acc2[a][b2]=(f32x4){0.f,0.f,0.f,0.f};

  for(int hg=0; hg<2; hg++){
    for(int hh=0; hh<4; hh++){
      int h = hg*4 + hh;
      f32x4 acc1[6];
      #pragma unroll
      for(int i=0;i<6;i++) acc1[i]=(f32x4){0.f,0.f,0.f,0.f};

      STAGE_QKV(h, 0, U);
      #pragma unroll
      for(int ks=0; ks<8; ks++){
        char* nxt = U + (((ks+1)&1) ? 24576u : 0u);
        if(ks<7) STAGE_QKV(h, ks+1, nxt);
        if(ks<7) asm volatile("s_waitcnt vmcnt(3)" ::: "memory");
        else     asm volatile("s_waitcnt vmcnt(0)" ::: "memory");
        FBAR();
        const char* bs = U + ((ks&1) ? 24576u : 0u);
        int arow = mt*16+lm;
        #pragma unroll
        for(int half=0; half<2; half++){
          short8 a = *(const short8*)(Abase + (unsigned)arow*1024u
                       + (((unsigned)(ks*128 + half*64 + lg*16)) ^ ((unsigned)(arow&7)<<4)));
          #pragma unroll
          for(int i=0;i<6;i++){
            int brow = (wb*6+i)*16+lm;
            short8 bb = *(const short8*)(bs + (unsigned)brow*128u
                         + (((unsigned)(half*64+lg*16)) ^ ((unsigned)(brow&7)<<4)));
            acc1[i] = MFMA_BF16(a, bb, acc1[i]);
          }
        }
        FBAR();
      }
      #pragma unroll
      for(int i=0;i<6;i++){
        int L = (wb*6+i)*16 + lm;
        int gc = (L<64)? h*64+L : (L<128)? 512+h*64+(L-64) : 1024+h*64+(L-128);
        float bia = bqkv[e*1536 + gc];
        #pragma unroll
        for(int rr=0;rr<4;rr++){
          int row = mt*16 + lg*4 + rr;
          QH[row*200 + L] = f2bf(acc1[i][rr] + bia);
        }
      }
      __syncthreads();
      {
        int r = t>>3, p = t&7, j = r>>3;
        float s = 0.f;
        #pragma unroll
        for(int dd=0; dd<64; dd+=8){
          bfpack8 qa; qa.v = *(const short8*)&QH[r*200 + dd];
          bfpack8 ka; ka.v = *(const short8*)&QH[(j*8+p)*200 + 64 + dd];
          #pragma unroll
          for(int ii=0;ii<8;ii++) s += bf2f(qa.u[ii])*bf2f(ka.u[ii]);
        }
        SC[r*8+p] = s * 0.125f;
      }
      __syncthreads();
      {
        int r = t>>3, p = t&7, j = r>>3;
        float sv[8]; float m = -1e30f;
        #pragma unroll
        for(int kk=0;kk<8;kk++){ sv[kk]=SC[r*8+kk]; m = fmaxf(m, sv[kk]); }
        float ssum = 0.f;
        #pragma unroll
        for(int kk=0;kk<8;kk++){ sv[kk]=__expf(sv[kk]-m); ssum += sv[kk]; }
        float inv = 1.f/ssum;
        float o[8] = {0.f,0.f,0.f,0.f,0.f,0.f,0.f,0.f};
        #pragma unroll
        for(int kk=0;kk<8;kk++){
          float pr = sv[kk]*inv;
          bfpack8 va; va.v = *(const short8*)&QH[(j*8+kk)*200 + 128 + p*8];
          #pragma unroll
          for(int ii=0;ii<8;ii++) o[ii] += pr * bf2f(va.u[ii]);
        }
        bfpack8 pk;
        #pragma unroll
        for(int ii=0;ii<8;ii++) pk.u[ii]=f2bf(o[ii]);
        *(short8*)(CTXb + (((unsigned)(r*512 + hh*128 + p*16)) ^ ((unsigned)(r&7)<<4))) = pk.v;
      }
      __syncthreads();
    }

    STAGE_WO(hg, 0, U);
    #pragma unroll
    for(int s=0; s<16; s++){
      int nh = s>>2, k2 = s&3;
      char* nxt = U + (((s+1)&1) ? 16384u : 0u);
      if(s<15) STAGE_WO(hg, s+1, nxt);
      if(s<15) asm volatile("s_waitcnt vmcnt(2)" ::: "memory");
      else     asm volatile("s_waitcnt vmcnt(0)" ::: "memory");
      FBAR();
      const char* bs = U + ((s&1) ? 16384u : 0u);
      int arow = mt*16+lm;
      #pragma unroll
      for(int half=0; half<2; half++){
        short8 a = *(const short8*)(CTXb + (unsigned)arow*512u
                     + (((unsigned)(k2*128 + half*64 + lg*16)) ^ ((unsigned)(arow&7)<<4)));
        #pragma unroll
        for(int i=0;i<4;i++){
          int brow = (wb*4+i)*16+lm;
          short8 bb = *(const short8*)(bs + (unsigned)brow*128u
                       + (((unsigned)(half*64+lg*16)) ^ ((unsigned)(brow&7)<<4)));
          acc2[nh][i] = MFMA_BF16(a, bb, acc2[nh][i]);
        }
      }
      FBAR();
    }
  }

  #pragma unroll
  for(int nh=0; nh<4; nh++)
    #pragma unroll
    for(int i=0;i<4;i++){
      int gcol = nh*128 + (wb*4+i)*16 + lm;
      float bia = bo[e*512 + gcol];
      #pragma unroll
      for(int rr=0;rr<4;rr++){
        int row = mt*16 + lg*4 + rr;
        int j2 = row>>3;
        int slot = (base+j2<ne)? jb[j2] : jb[0];
        int b = slot>>1, n = row&7;
        float tok = (gcol<256)? lat[((size_t)b*8+n)*256 + gcol]
                              : act[((size_t)b*8+n)*256 + gcol - 256];
        *(unsigned short*)(Abase + (((unsigned)(row*1024 + gcol*2)) ^ ((unsigned)(row&7)<<4)))
            = f2bf(acc2[nh][i][rr] + bia + tok);
      }
    }
  __syncthreads();
  {
    int r = t>>3, p = t&7;
    unsigned rsw = ((unsigned)(r&7))<<4;
    bfpack8 xv[8];
    float sum=0.f, sq=0.f;
    #pragma unroll
    for(int j=0;j<8;j++){
      xv[j].v = *(const short8*)(Abase + (((unsigned)(r*1024 + j*128 + p*16)) ^ rsw));
      #pragma unroll
      for(int ii=0;ii<8;ii++){ float f = bf2f(xv[j].u[ii]); sum += f; sq += f*f; }
    }
    sum += __shfl_xor(sum,1); sq += __shfl_xor(sq,1);
    sum += __shfl_xor(sum,2); sq += __shfl_xor(sq,2);
    sum += __shfl_xor(sum,4); sq += __shfl_xor(sq,4);
    float mu = sum*(1.f/512.f);
    float var = sq*(1.f/512.f) - mu*mu;
    float rstd = rsqrtf(var + LN_EPS);
    int j8 = r>>3;
    if(base + j8 < ne){
      int slot = jb[j8]; int n = r&7;
      unsigned short* dst = &x_bf[((size_t)slot*8+n)*512];
      #pragma unroll
      for(int j=0;j<8;j++){
        bfpack8 pk;
        #pragma unroll
        for(int ii=0;ii<8;ii++){
          int gc = j*64 + p*8 + ii;
          float xvv = (bf2f(xv[j].u[ii]) - mu)*rstd*ln1g[e*512+gc] + ln1b[e*512+gc];
          pk.u[ii] = f2bf(xvv);
        }
        *(short8*)&dst[j*64 + p*8] = pk.v;
      }
    }
  }
}

// ============ expert FFN v5.1: identical to v5 but launch_bounds (512,2) — no VGPR cap spill ============
// 512 thr, 8 waves 2m x 4n; wave tile 32 rows x 32 cols (ns=2).
// LDS: BS dbuf 2x16KB @0, HC [64][136] bf16 @32768 (17408B). PL [64][520] overlays all (66560B).
// 66.5KB LDS x2 fits/CU; VGPR ~110 <= 128 -> HW can schedule 2 blocks/CU (4 waves/SIMD).
#define E2_LDS 66560
#define E2_HP  136

#define FFN_STAGE_W1(cc, kk, dst) do{ \
    unsigned _Lw = (unsigned)w*2048u; \
    _Pragma("unroll") \
    for(int _q=0;_q<2;_q++){ \
      unsigned _L = _Lw + (unsigned)_q*1024u + (unsigned)lane*16u; \
      int _row = (int)(_L>>7); unsigned _pb = _L&127u; \
      const char* _g = W1 + (size_t)((cc)*128+_row)*1024 + (kk)*128 + (_pb ^ ((unsigned)(_row&7)<<4)); \
      gload16(_g, (dst) + (_Lw + (unsigned)_q*1024u)); \
    } }while(0)

#define FFN_STAGE_W2(cc, nn, kk, dst) do{ \
    unsigned _Lw = (unsigned)w*2048u; \
    _Pragma("unroll") \
    for(int _q=0;_q<2;_q++){ \
      unsigned _L = _Lw + (unsigned)_q*1024u + (unsigned)lane*16u; \
      int _row = (int)(_L>>7); unsigned _pb = _L&127u; \
      const char* _g = W2 + (size_t)((nn)*128+_row)*4096 + ((cc)*128+(kk)*64)*2 \
                     + (_pb ^ ((unsigned)(_row&7)<<4)); \
      gload16(_g, (dst) + (_Lw + (unsigned)_q*1024u)); \
    } }while(0)

__global__ __launch_bounds__(512,2) void k_expert_ffn(
    const unsigned short* __restrict__ x_bf,
    const unsigned short* __restrict__ Wf1_t, const float* __restrict__ bf1,
    const unsigned short* __restrict__ Wf2_t, const float* __restrict__ bf2v,
    const float* __restrict__ ln2g, const float* __restrict__ ln2b,
    const int* __restrict__ jobs, const int* __restrict__ cnt,
    unsigned short* __restrict__ slot_out){
  extern __shared__ char smem[];
  char* BSB0 = smem;
  char* BSB1 = smem + 16384;
  unsigned short* HC = (unsigned short*)(smem + 32768);
  unsigned short* PL = (unsigned short*)smem;   // overlay after K-loops

  // balanced XCD map: XCD pair (2e,2e+1) owns expert e
  int bid = blockIdx.x;
  int e   = (bid&7)>>1;
  int blk = ((bid>>3)<<1) | (bid&1);
  int ne = cnt[e];
  int base = blk*8;
  if(base >= ne) return;
  int t = threadIdx.x;
  int w = t>>6, lane = t&63, lg = lane>>4, lm = lane&15;
  int mg = w>>2, ng = w&3;                    // 2m x 4n wave grid
  const int* jb = &jobs[e*2048 + base];
  unsigned bswz = ((unsigned)(lm&7))<<4;      // B-read swizzle (brow&7 == lm&7)

  const char* W1 = (const char*)(Wf1_t + (size_t)e*2048*512);
  const char* W2 = (const char*)(Wf2_t + (size_t)e*512*2048);

  // per-lane x base addresses for A-frags (row = mg*32 + ms*16 + lm)
  const char* xb[2];
  #pragma unroll
  for(int ms=0;ms<2;ms++){
    int row = mg*32 + ms*16 + lm;
    int j = row>>3;
    int slot = (base+j<ne)? jb[j] : jb[0];
    int n = row&7;
    xb[ms] = (const char*)x_bf + (((size_t)slot*8+n)<<10) + (size_t)(lg*16);
  }

  // x-frag double buffer: xf[parity][ms][half]
  short8 xf[2][2][2];
  #pragma unroll
  for(int ms=0;ms<2;ms++)
    #pragma unroll
    for(int hf=0;hf<2;hf++)
      xf[0][ms][hf] = *(const short8*)(xb[ms] + hf*64);

  f32x4 acc[4][2][2];   // [nh][ms][ns] persistent G2 accumulator (64 VGPR)
  #pragma unroll
  for(int a=0;a<4;a++)
    #pragma unroll
    for(int b=0;b<2;b++)
      #pragma unroll
      for(int c2=0;c2<2;c2++) acc[a][b][c2]=(f32x4){0.f,0.f,0.f,0.f};

  // prologue
  FFN_STAGE_W1(0, 0, BSB0);

  for(int c=0; c<16; c++){
    f32x4 acc1[2][2];
    #pragma unroll
    for(int b=0;b<2;b++)
      #pragma unroll
      for(int c2=0;c2<2;c2++) acc1[b][c2]=(f32x4){0.f,0.f,0.f,0.f};

    // ---- G1: h_c[64][128] = x @ W1[:, c*128..+128], 8 k-steps
    #pragma unroll
    for(int ks=0; ks<8; ks++){
      // x-frag prefetch FIRST (older than stage -> reg-dep wait stays loose)
      #pragma unroll
      for(int ms=0;ms<2;ms++)
        #pragma unroll
        for(int hf=0;hf<2;hf++)
          xf[(ks+1)&1][ms][hf] = *(const short8*)(xb[ms] + (((ks+1)&7)*128 + hf*64));
      char* nxt = ((ks+1)&1) ? BSB1 : BSB0;
      if(ks<7) FFN_STAGE_W1(c, ks+1, nxt);
      else     FFN_STAGE_W2(c, 0, 0, nxt);
      asm volatile("s_waitcnt vmcnt(6)" ::: "memory");
      FBAR();
      const char* bs = (ks&1) ? BSB1 : BSB0;
      #pragma unroll
      for(int hf=0;hf<2;hf++){
        #pragma unroll
        for(int ns=0;ns<2;ns++){
          unsigned boff = (unsigned)((ng*32+ns*16+lm)*128);
          short8 bb = *(const short8*)(bs + boff + (((unsigned)(hf*64+lg*16)) ^ bswz));
          acc1[0][ns] = MFMA_BF16(xf[ks&1][0][hf], bb, acc1[0][ns]);
          acc1[1][ns] = MFMA_BF16(xf[ks&1][1][hf], bb, acc1[1][ns]);
        }
      }
      if(ks==7){
        #pragma unroll
        for(int ms=0;ms<2;ms++)
          #pragma unroll
          for(int ns=0;ns<2;ns++){
            int colL = ng*32 + ns*16 + lm;
            float bia = bf1[e*2048 + c*128 + colL];
            #pragma unroll
            for(int rr=0;rr<4;rr++){
              int row = mg*32 + ms*16 + lg*4 + rr;
              HC[row*E2_HP + colL] = f2bf(fmaxf(acc1[ms][ns][rr] + bia, 0.f));
            }
          }
        asm volatile("s_waitcnt lgkmcnt(0)" ::: "memory");
      }
      FBAR();
    }

    // ---- G2: acc += h_c @ W2[c-chunk k, :]; 8 steps (nh 0..3 x k2 0..1)
    #pragma unroll
    for(int s2=0; s2<8; s2++){
      const int nh = s2>>1, k2 = s2&1;
      char* nxt = ((s2+1)&1) ? BSB1 : BSB0;
      if(s2<7)       FFN_STAGE_W2(c, (s2+1)>>1, (s2+1)&1, nxt);
      else if(c<15)  FFN_STAGE_W1(c+1, 0, nxt);
      if(s2<7 || c<15) asm volatile("s_waitcnt vmcnt(2)" ::: "memory");
      else             asm volatile("s_waitcnt vmcnt(0)" ::: "memory");
      FBAR();
      const char* bs = (s2&1) ? BSB1 : BSB0;
      #pragma unroll
      for(int hf=0;hf<2;hf++){
        short8 ha0 = *(const short8*)&HC[(mg*32 +      lm)*E2_HP + k2*64 + hf*32 + lg*8];
        short8 ha1 = *(const short8*)&HC[(mg*32 + 16 + lm)*E2_HP + k2*64 + hf*32 + lg*8];
        #pragma unroll
        for(int ns=0;ns<2;ns++){
          unsigned boff = (unsigned)((ng*32+ns*16+lm)*128);
          short8 bb = *(const short8*)(bs + boff + (((unsigned)(hf*64+lg*16)) ^ bswz));
          acc[nh][0][ns] = MFMA_BF16(ha0, bb, acc[nh][0][ns]);
          acc[nh][1][ns] = MFMA_BF16(ha1, bb, acc[nh][1][ns]);
        }
      }
      FBAR();
    }
  }

  // ---- PL = acc + bf2 (residual added in LN phase from global) ----
  #pragma unroll
  for(int nh=0;nh<4;nh++)
    #pragma unroll
    for(int ms=0;ms<2;ms++)
      #pragma unroll
      for(int ns=0;ns<2;ns++){
        int col = nh*128 + ng*32 + ns*16 + lm;
        float bia = bf2v[e*512+col];
        #pragma unroll
        for(int rr=0;rr<4;rr++){
          int row = mg*32 + ms*16 + lg*4 + rr;
          PL[row*520 + col] = f2bf(acc[nh][ms][ns][rr] + bia);
        }
      }
  __syncthreads();

  // ---- LN2 (+global residual) -> slot_out ----
  {
    int r = t>>3, p = t&7;
    int j8 = r>>3;
    int slot = (base + j8 < ne) ? jb[j8] : jb[0];
    int n = r&7;
    const unsigned short* xg = &x_bf[((size_t)slot*8+n)*512];
    bfpack8 cv[8];
    float sum=0.f, sq=0.f;
    #pragma unroll
    for(int j=0;j<8;j++){
      bfpack8 pa; pa.v = *(const short8*)&PL[r*520 + j*64 + p*8];
      bfpack8 xa; xa.v = *(const short8*)&xg[j*64 + p*8];
      #pragma unroll
      for(int ii=0;ii<8;ii++){
        float f = bf2f(pa.u[ii]) + bf2f(xa.u[ii]);
        cv[j].u[ii] = f2bf(f);
        f = bf2f(cv[j].u[ii]);
        sum += f; sq += f*f;
      }
    }
    sum += __shfl_xor(sum,1); sq += __shfl_xor(sq,1);
    sum += __shfl_xor(sum,2); sq += __shfl_xor(sq,2);
    sum += __shfl_xor(sum,4); sq += __shfl_xor(sq,4);
    float mu = sum*(1.f/512.f);
    float var = sq*(1.f/512.f) - mu*mu;
    float rstd = rsqrtf(var + LN_EPS);
    if(base + j8 < ne){
      unsigned short* dst = &slot_out[((size_t)slot*8+n)*512];
      #pragma unroll
      for(int j=0;j<8;j++){
        bfpack8 pk;
        #pragma unroll
        for(int ii=0;ii<8;ii++){
          int gc = j*64 + p*8 + ii;
          float xv = (bf2f(cv[j].u[ii]) - mu)*rstd*ln2g[e*512+gc] + ln2b[e*512+gc];
          pk.u[ii] = f2bf(xv);
        }
        *(short8*)&dst[j*64 + p*8] = pk.v;
      }
    }
  }
}

// ============ combine: mixed_bf[b][d] = w0*out[2b][d] + w1*out[2b+1][d] ============
__global__ __launch_bounds__(256) void k_combine(const unsigned short* __restrict__ so,
    const float* __restrict__ slotw, unsigned short* __restrict__ mx){
  int gid = blockIdx.x*256 + threadIdx.x;
  int b = gid >> 9, c8 = gid & 511;
  float w0 = slotw[b*2+0], w1 = slotw[b*2+1];
  bfpack8 x0; x0.v = *(const short8*)&so[((size_t)(b*2+0))*4096 + c8*8];
  bfpack8 x1; x1.v = *(const short8*)&so[((size_t)(b*2+1))*4096 + c8*8];
  bfpack8 o;
  #pragma unroll
  for(int j=0;j<8;j++) o.u[j] = f2bf(w0*bf2f(x0.u[j]) + w1*bf2f(x1.u[j]));
  *(short8*)&mx[(size_t)b*4096 + c8*8] = o.v;
}

// ============ head GEMM 1: hidden = relu(mixed_bf @ hW1 + b1) ============
#define H_SP 72
__global__ __launch_bounds__(256) void k_head1(const unsigned short* __restrict__ mixbf,
    const unsigned short* __restrict__ hW1t, const float* __restrict__ b1,
    unsigned short* __restrict__ hidden){
  __shared__ unsigned short As[64*H_SP], Bs[64*H_SP];
  int n0 = blockIdx.x*64, m0 = blockIdx.y*64;
  int t = threadIdx.x, w = t>>6, lane = t&63, lg = lane>>4, lm = lane&15;
  f32x4 acc[4]; for(int i=0;i<4;i++) acc[i]=(f32x4){0.f,0.f,0.f,0.f};
  for(int ks=0; ks<64; ks++){
    __syncthreads();
    int k0 = ks*64;
    for(int i=0;i<2;i++){
      int u = i*256 + t; int row = u>>3, ch = u&7;
      *(short8*)&As[row*H_SP + ch*8] = *(const short8*)&mixbf[(size_t)(m0+row)*4096 + k0 + ch*8];
    }
    for(int i=0;i<2;i++){
      int u = i*256 + t; int row = u>>3, ch = u&7;
      *(short8*)&Bs[row*H_SP + ch*8] = *(const short8*)&hW1t[(size_t)(n0+row)*4096 + k0 + ch*8];
    }
    __syncthreads();
    for(int half=0; half<2; half++){
      short8 a = *(const short8*)&As[(w*16+lm)*H_SP + half*32 + lg*8];
      for(int i=0;i<4;i++){
        short8 bb = *(const short8*)&Bs[(i*16+lm)*H_SP + half*32 + lg*8];
        acc[i] = MFMA_BF16(a, bb, acc[i]);
      }
    }
  }
  for(int i=0;i<4;i++){
    int gc = n0 + i*16 + lm; float bia = b1[gc];
    for(int rr=0; rr<4; rr++){
      int row = m0 + w*16 + lg*4 + rr;
      hidden[(size_t)row*512 + gc] = f2bf(fmaxf(acc[i][rr] + bia, 0.f));
    }
  }
}

// ============ head GEMM 2: logits = hidden @ hW2 + b2 ============
__global__ __launch_bounds__(256) void k_head2(const unsigned short* __restrict__ hidden,
    const unsigned short* __restrict__ hW2t, const float* __restrict__ b2,
    float* __restrict__ out){
  __shared__ unsigned short As[64*H_SP], Bs[112*H_SP];
  int m0 = blockIdx.x*64;
  int t = threadIdx.x, w = t>>6, lane = t&63, lg = lane>>4, lm = lane&15;
  f32x4 acc[7]; for(int i=0;i<7;i++) acc[i]=(f32x4){0.f,0.f,0.f,0.f};
  for(int ks=0; ks<8; ks++){
    __syncthreads();
    int k0 = ks*64;
    for(int i=0;i<2;i++){
      int u = i*256 + t; int row = u>>3, ch = u&7;
      *(short8*)&As[row*H_SP + ch*8] = *(const short8*)&hidden[(size_t)(m0+row)*512 + k0 + ch*8];
    }
    for(int i=0;i<4;i++){
      int u = i*256 + t;
      if(u < 896){
        int row = u>>3, ch = u&7;
        *(short8*)&Bs[row*H_SP + ch*8] = *(const short8*)&hW2t[(size_t)row*512 + k0 + ch*8];
      }
    }
    __syncthreads();
    for(int half=0; half<2; half++){
      short8 a = *(const short8*)&As[(w*16+lm)*H_SP + half*32 + lg*8];
      for(int i=0;i<7;i++){
        short8 bb = *(const short8*)&Bs[(i*16+lm)*H_SP + half*32 + lg*8];
        acc[i] = MFMA_BF16(a, bb, acc[i]);
      }
    }
  }
  for(int i=0;i<7;i++){
    int col = i*16 + lm;
    if(col < 101){
      float bia = b2[col];
      for(int rr=0; rr<4; rr++){
        int row = m0 + w*16 + lg*4 + rr;
        out[(size_t)row*101 + col] = acc[i][rr] + bia;
      }
    }
  }
}

// ================= host launcher =================
extern "C" void kernel_launch(void* const* d_in, const int* in_sizes, int n_in,
                              void* d_out, int out_size, void* d_ws, size_t ws_size,
                              hipStream_t stream){
  if(ws_size < WS_NEED) return;
  const float* lat  = (const float*)d_in[0];
  const float* act  = (const float*)d_in[1];
  const float* gateW= (const float*)d_in[2];
  const float* Wqkv = (const float*)d_in[3];
  const float* bqkv = (const float*)d_in[4];
  const float* Wo   = (const float*)d_in[5];
  const float* bo   = (const float*)d_in[6];
  const float* ln1g = (const float*)d_in[7];
  const float* ln1b = (const float*)d_in[8];
  const float* Wf1  = (const float*)d_in[9];
  const float* bf1  = (const float*)d_in[10];
  const float* Wf2  = (const float*)d_in[11];
  const float* bf2v = (const float*)d_in[12];
  const float* ln2g = (const float*)d_in[13];
  const float* ln2b = (const float*)d_in[14];
  const float* hW1  = (const float*)d_in[15];
  const float* hb1  = (const float*)d_in[16];
  const float* hW2  = (const float*)d_in[17];
  const float* hb2  = (const float*)d_in[18];
  float* out = (float*)d_out;
  char* ws = (char*)d_ws;

  unsigned short* WQKVT = (unsigned short*)(ws + OFF_WQKVT);
  unsigned short* WOT   = (unsigned short*)(ws + OFF_WOT);
  unsigned short* WF1T  = (unsigned short*)(ws + OFF_WF1T);
  unsigned short* WF2T  = (unsigned short*)(ws + OFF_WF2T);
  unsigned short* HW1T  = (unsigned short*)(ws + OFF_HW1T);
  unsigned short* HW2T  = (unsigned short*)(ws + OFF_HW2T);
  unsigned short* XBF   = (unsigned short*)(ws + OFF_XBF);   // x after LN1; reused as MIXEDBF
  unsigned short* SLOTO = (unsigned short*)(ws + OFF_SLOTO);
  unsigned short* MIXBF = XBF;
  unsigned short* HID = (unsigned short*)(ws + OFF_HID);
  int* JOBS = (int*)(ws + OFF_JOBS);
  float* SLOTW = (float*)(ws + OFF_SLOTW);
  float* LSE = (float*)(ws + OFF_LSE);
  int* CNT = (int*)(ws + OFF_CNT);

  (void)hipFuncSetAttribute((const void*)k_expert_attn,
      hipFuncAttributeMaxDynamicSharedMemorySize, AT_LDS);
  (void)hipFuncSetAttribute((const void*)k_expert_ffn,
      hipFuncAttributeMaxDynamicSharedMemorySize, E2_LDS);

  hipMemsetAsync(CNT, 0, 16, stream);
  hipMemsetAsync(HW2T, 0, 112*512*2, stream);

  // weight transposes (fp32 -> bf16, [R][C] -> [C][R])
  k_transpose_cast<<<dim3(48,16,4),256,0,stream>>>(Wqkv, WQKVT, 512, 1536);
  k_transpose_cast<<<dim3(16,16,4),256,0,stream>>>(Wo,   WOT,   512, 512);
  k_transpose_cast<<<dim3(64,16,4),256,0,stream>>>(Wf1,  WF1T,  512, 2048);
  k_transpose_cast<<<dim3(16,64,4),256,0,stream>>>(Wf2,  WF2T,  2048, 512);
  k_transpose_cast<<<dim3(16,128,1),256,0,stream>>>(hW1, HW1T,  4096, 512);
  k_transpose_cast<<<dim3(4,16,1),256,0,stream>>>(hW2,  HW2T,  512, 101);

  k_router<<<2048,256,0,stream>>>(lat, act, gateW, out + OUT_GATES, JOBS, CNT, SLOTW, LSE);
  k_finalize<<<1,256,0,stream>>>(out + OUT_GATES, LSE, CNT, out + OUT_LBL);

  k_expert_attn<<<1024, 512, AT_LDS, stream>>>(lat, act, WQKVT, bqkv, WOT, bo,
      ln1g, ln1b, JOBS, CNT, XBF);
  k_expert_ffn<<<1024, 512, E2_LDS, stream>>>(XBF, WF1T, bf1, WF2T, bf2v,
      ln2g, ln2b, JOBS, CNT, SLOTO);
  k_combine<<<4096,256,0,stream>>>(SLOTO, SLOTW, MIXBF);

  k_head1<<<dim3(8,32),256,0,stream>>>(MIXBF, HW1T, hb1, HID);
  k_head2<<<32,256,0,stream>>>(HID, HW2T, hb2, out);
}

// Round 11
// 780.698 us; speedup vs baseline: 1.3774x; 1.2576x over previous
//
#include <hip/hip_runtime.h>
#include <stdint.h>

// ---------------- problem constants ----------------
#define NB    2048
#define NAG   8
#define NEXP  4
#define LN_EPS 1e-5f

#define OUT_GATES  (2048*101)            // 206848
#define OUT_LBL    (OUT_GATES + 2048*4)  // 215040

typedef __attribute__((ext_vector_type(8))) short short8;
typedef __attribute__((ext_vector_type(4))) float f32x4;

#define MFMA_BF16(a,b,c) __builtin_amdgcn_mfma_f32_16x16x32_bf16((a),(b),(c),0,0,0)

__device__ __forceinline__ float bf2f(unsigned short h){
  union { unsigned int u; float f; } v; v.u = ((unsigned int)h) << 16; return v.f;
}
__device__ __forceinline__ unsigned short f2bf(float x){
  union { float f; unsigned int u; } v; v.f = x;
  unsigned int r = v.u + 0x7FFFu + ((v.u >> 16) & 1u);
  return (unsigned short)(r >> 16);
}
union bfpack8 { short8 v; unsigned short u[8]; };

// async global->LDS DMA, 16B per lane; LDS dest = wave-uniform base + lane*16
__device__ __forceinline__ void gload16(const void* g, void* l){
  __builtin_amdgcn_global_load_lds(
      (const __attribute__((address_space(1))) void*)g,
      (__attribute__((address_space(3))) void*)l, 16, 0, 0);
}

// raw barrier with compiler memory fences (no vmcnt drain!)
#define FBAR() do{ asm volatile("" ::: "memory"); \
                   __builtin_amdgcn_s_barrier(); \
                   asm volatile("" ::: "memory"); }while(0)

// ---------------- workspace layout (bytes) ----------------
#define OFF_WQKVT  0ULL                      // [4][1536][512] bf16
#define OFF_WOT    6291456ULL                // [4][512][512]
#define OFF_WF1T   8388608ULL                // [4][2048][512]
#define OFF_WF2T   16777216ULL               // [4][512][2048]
#define OFF_HW1T   25165824ULL               // [512][4096]
#define OFF_HW2T   29360128ULL               // [112][512] (zero-padded rows)
#define OFF_XBF    29474816ULL               // [4096][8][512] bf16 (x after LN1); MIXEDBF overlays after FFN
#define OFF_SLOTO  63029248ULL               // [4096][4096] bf16 per-slot LN2 out
#define OFF_HID    96583680ULL               // [2048][512] bf16
#define OFF_JOBS   98680832ULL               // int[4][2048] slot ids (slot=b*2+s)
#define OFF_SLOTW  98713600ULL               // float[4096] gate weight per slot
#define OFF_LSE    98729984ULL               // float[2048]
#define OFF_CNT    98738176ULL               // int[4]
#define WS_NEED    98738192ULL

// ============ transpose+cast: src f32 [E][R][C] -> dst bf16 [E][C][R] ============
__global__ __launch_bounds__(256) void k_transpose_cast(const float* __restrict__ src,
    unsigned short* __restrict__ dst, int R, int C){
  __shared__ float tile[32][33];
  int e = blockIdx.z;
  int c0 = blockIdx.x*32, r0 = blockIdx.y*32;
  const float* s = src + (size_t)e*R*C;
  unsigned short* d = dst + (size_t)e*C*R;
  int tx = threadIdx.x & 31, ty = threadIdx.x >> 5;
  for(int yy = ty; yy < 32; yy += 8){
    int r = r0+yy, c = c0+tx;
    if(r<R && c<C) tile[yy][tx] = s[(size_t)r*C + c];
  }
  __syncthreads();
  for(int yy = ty; yy < 32; yy += 8){
    int oc = c0+yy, orr = r0+tx;
    if(oc<C && orr<R) d[(size_t)oc*R + orr] = f2bf(tile[tx][yy]);
  }
}

// ============ router: logits, top2 gates, job lists, lse ============
__global__ __launch_bounds__(256) void k_router(const float* __restrict__ lat,
    const float* __restrict__ act, const float* __restrict__ gateW,
    float* __restrict__ gates_out, int* __restrict__ jobs, int* __restrict__ cnt,
    float* __restrict__ slot_w, float* __restrict__ lse_arr){
  int b = blockIdx.x, t = threadIdx.x;
  float a0=0.f,a1=0.f,a2=0.f,a3=0.f;
  for(int i=t;i<4096;i+=256){
    int n=i>>9, d=i&511;
    float v = (d<256)? lat[((size_t)b*8+n)*256 + d] : act[((size_t)b*8+n)*256 + (d-256)];
    float4 gw = *(const float4*)&gateW[(size_t)i*4];
    a0 += v*gw.x; a1 += v*gw.y; a2 += v*gw.z; a3 += v*gw.w;
  }
  __shared__ float red[4][256];
  red[0][t]=a0; red[1][t]=a1; red[2][t]=a2; red[3][t]=a3;
  __syncthreads();
  for(int s=128;s>0;s>>=1){
    if(t<s){ red[0][t]+=red[0][t+s]; red[1][t]+=red[1][t+s]; red[2][t]+=red[2][t+s]; red[3][t]+=red[3][t+s]; }
    __syncthreads();
  }
  if(t==0){
    float lg[4] = {red[0][0], red[1][0], red[2][0], red[3][0]};
    int i1=0; for(int e=1;e<4;e++) if(lg[e]>lg[i1]) i1=e;
    int i2=-1; for(int e=0;e<4;e++){ if(e==i1) continue; if(i2<0 || lg[e]>lg[i2]) i2=e; }
    float m = lg[i1];
    float e2 = __expf(lg[i2]-m);
    float inv = 1.f/(1.f+e2);
    float w1 = inv, w2 = e2*inv;
    float g[4]={0.f,0.f,0.f,0.f}; g[i1]=w1; g[i2]=w2;
    gates_out[b*4+0]=g[0]; gates_out[b*4+1]=g[1]; gates_out[b*4+2]=g[2]; gates_out[b*4+3]=g[3];
    float s=0.f; for(int e=0;e<4;e++) s += __expf(lg[e]-m);
    lse_arr[b] = m + __logf(s);
    int p1 = atomicAdd(&cnt[i1],1); jobs[i1*2048+p1] = b*2+0; slot_w[b*2+0] = w1;
    int p2 = atomicAdd(&cnt[i2],1); jobs[i2*2048+p2] = b*2+1; slot_w[b*2+1] = w2;
  }
}

// ============ finalize: load-balance loss ============
__global__ __launch_bounds__(256) void k_finalize(const float* __restrict__ gates,
    const float* __restrict__ lse_arr, const int* __restrict__ cnt, float* __restrict__ lbl){
  __shared__ float r0[256], r1[256], r2[256], r3[256], rl[256];
  int t = threadIdx.x;
  float g0=0.f,g1=0.f,g2=0.f,g3=0.f,l=0.f;
  for(int b=t;b<2048;b+=256){
    g0+=gates[b*4+0]; g1+=gates[b*4+1]; g2+=gates[b*4+2]; g3+=gates[b*4+3];
    l += lse_arr[b];
  }
  r0[t]=g0;r1[t]=g1;r2[t]=g2;r3[t]=g3;rl[t]=l;
  __syncthreads();
  for(int s=128;s>0;s>>=1){
    if(t<s){ r0[t]+=r0[t+s]; r1[t]+=r1[t+s]; r2[t]+=r2[t+s]; r3[t]+=r3[t+s]; rl[t]+=rl[t+s]; }
    __syncthreads();
  }
  if(t==0){
    float gs[4]={r0[0],r1[0],r2[0],r3[0]};
    float ld[4]={(float)cnt[0],(float)cnt[1],(float)cnt[2],(float)cnt[3]};
    float mu1=(gs[0]+gs[1]+gs[2]+gs[3])*0.25f;
    float v1=0.f; for(int i=0;i<4;i++){float d=gs[i]-mu1; v1+=d*d;} v1 *= (1.f/3.f);
    float mu2=(ld[0]+ld[1]+ld[2]+ld[3])*0.25f;
    float v2=0.f; for(int i=0;i<4;i++){float d=ld[i]-mu2; v2+=d*d;} v2 *= (1.f/3.f);
    lbl[0] = v1/(mu1*mu1+1e-10f) + v2/(mu2*mu2+1e-10f) + rl[0]*(1.f/2048.f);
  }
}

// ============ expert attention v3 (unchanged) ============
#define AT_LDS 149504

#define STAGE_QKV(hh_, ks_, dst_) do{ \
    _Pragma("unroll") \
    for(int _q=0;_q<3;_q++){ \
      unsigned _L = (unsigned)w*3072u + (unsigned)_q*1024u + (unsigned)lane*16u; \
      int _row = (int)(_L>>7); unsigned _pb = _L & 127u; \
      int _gc = (_row<64)? (hh_)*64+_row : (_row<128)? 512+(hh_)*64+(_row-64) : 1024+(hh_)*64+(_row-128); \
      const char* _g = Wq + (size_t)_gc*1024 + (ks_)*128 + (_pb ^ ((unsigned)(_row&7)<<4)); \
      gload16(_g, (dst_) + ((unsigned)w*3072u + (unsigned)_q*1024u)); \
    } }while(0)

#define STAGE_WO(hg_, s_, dst_) do{ \
    int _nh = (s_)>>2, _k2 = (s_)&3; \
    _Pragma("unroll") \
    for(int _q=0;_q<2;_q++){ \
      unsigned _L = (unsigned)w*2048u + (unsigned)_q*1024u + (unsigned)lane*16u; \
      int _row = (int)(_L>>7); unsigned _pb = _L & 127u; \
      const char* _g = WoP + (size_t)(_nh*128+_row)*1024 + (hg_)*512 + _k2*128 \
                     + (_pb ^ ((unsigned)(_row&7)<<4)); \
      gload16(_g, (dst_) + ((unsigned)w*2048u + (unsigned)_q*1024u)); \
    } }while(0)

__global__ __launch_bounds__(512,2) void k_expert_attn(
    const float* __restrict__ lat, const float* __restrict__ act,
    const unsigned short* __restrict__ Wqkv_t, const float* __restrict__ bqkv,
    const unsigned short* __restrict__ Wo_t,   const float* __restrict__ bo,
    const float* __restrict__ ln1g, const float* __restrict__ ln1b,
    const int* __restrict__ jobs, const int* __restrict__ cnt,
    unsigned short* __restrict__ x_bf){
  extern __shared__ char smem[];
  char* Abase = smem;                    // tokens, later XP (preLN)
  char* CTXb  = smem + 65536;            // [64] x 512B
  char* U     = smem + 98304;            // 48KB dbuf / QH union
  float* SC   = (float*)(smem + 147456); // [64][8]

  int bid = blockIdx.x;
  int e   = (bid&7)>>1;
  int blk = ((bid>>3)<<1) | (bid&1);
  int ne = cnt[e];
  int base = blk*8;
  if(base >= ne) return;
  int t = threadIdx.x;
  int w = t>>6, lane = t&63, lg = lane>>4, lm = lane&15;
  int mt = w>>1, wb = w&1;
  const int* jb = &jobs[e*2048 + base];

  #pragma unroll
  for(int i=0;i<8;i++){
    int u = i*512 + t; int row = u>>6, ch = u&63; int d0 = ch*8;
    int j = row>>3;
    int slot = (base + j < ne) ? jb[j] : jb[0];
    int b = slot>>1, n = row&7;
    const float* src = (d0<256)? &lat[((size_t)b*8+n)*256 + d0]
                               : &act[((size_t)b*8+n)*256 + (d0-256)];
    float4 f0 = *(const float4*)src; float4 f1 = *(const float4*)(src+4);
    bfpack8 pk;
    pk.u[0]=f2bf(f0.x); pk.u[1]=f2bf(f0.y); pk.u[2]=f2bf(f0.z); pk.u[3]=f2bf(f0.w);
    pk.u[4]=f2bf(f1.x); pk.u[5]=f2bf(f1.y); pk.u[6]=f2bf(f1.z); pk.u[7]=f2bf(f1.w);
    *(short8*)(Abase + (((unsigned)(row*1024 + ch*16)) ^ ((unsigned)(row&7)<<4))) = pk.v;
  }
  asm volatile("s_waitcnt lgkmcnt(0)" ::: "memory");

  const char* Wq  = (const char*)(Wqkv_t + (size_t)e*1536*512);
  const char* WoP = (const char*)(Wo_t   + (size_t)e*512*512);
  unsigned short* QH = (unsigned short*)U;

  f32x4 acc2[4][4];
  #pragma unroll
  for(int a=0;a<4;a++)
    #pragma unroll
    for(int b2=0;b2<4;b2++) acc2[a][b2]=(f32x4){0.f,0.f,0.f,0.f};

  for(int hg=0; hg<2; hg++){
    for(int hh=0; hh<4; hh++){
      int h = hg*4 + hh;
      f32x4 acc1[6];
      #pragma unroll
      for(int i=0;i<6;i++) acc1[i]=(f32x4){0.f,0.f,0.f,0.f};

      STAGE_QKV(h, 0, U);
      #pragma unroll
      for(int ks=0; ks<8; ks++){
        char* nxt = U + (((ks+1)&1) ? 24576u : 0u);
        if(ks<7) STAGE_QKV(h, ks+1, nxt);
        if(ks<7) asm volatile("s_waitcnt vmcnt(3)" ::: "memory");
        else     asm volatile("s_waitcnt vmcnt(0)" ::: "memory");
        FBAR();
        const char* bs = U + ((ks&1) ? 24576u : 0u);
        int arow = mt*16+lm;
        #pragma unroll
        for(int half=0; half<2; half++){
          short8 a = *(const short8*)(Abase + (unsigned)arow*1024u
                       + (((unsigned)(ks*128 + half*64 + lg*16)) ^ ((unsigned)(arow&7)<<4)));
          #pragma unroll
          for(int i=0;i<6;i++){
            int brow = (wb*6+i)*16+lm;
            short8 bb = *(const short8*)(bs + (unsigned)brow*128u
                         + (((unsigned)(half*64+lg*16)) ^ ((unsigned)(brow&7)<<4)));
            acc1[i] = MFMA_BF16(a, bb, acc1[i]);
          }
        }
        FBAR();
      }
      #pragma unroll
      for(int i=0;i<6;i++){
        int L = (wb*6+i)*16 + lm;
        int gc = (L<64)? h*64+L : (L<128)? 512+h*64+(L-64) : 1024+h*64+(L-128);
        float bia = bqkv[e*1536 + gc];
        #pragma unroll
        for(int rr=0;rr<4;rr++){
          int row = mt*16 + lg*4 + rr;
          QH[row*200 + L] = f2bf(acc1[i][rr] + bia);
        }
      }
      __syncthreads();
      {
        int r = t>>3, p = t&7, j = r>>3;
        float s = 0.f;
        #pragma unroll
        for(int dd=0; dd<64; dd+=8){
          bfpack8 qa; qa.v = *(const short8*)&QH[r*200 + dd];
          bfpack8 ka; ka.v = *(const short8*)&QH[(j*8+p)*200 + 64 + dd];
          #pragma unroll
          for(int ii=0;ii<8;ii++) s += bf2f(qa.u[ii])*bf2f(ka.u[ii]);
        }
        SC[r*8+p] = s * 0.125f;
      }
      __syncthreads();
      {
        int r = t>>3, p = t&7, j = r>>3;
        float sv[8]; float m = -1e30f;
        #pragma unroll
        for(int kk=0;kk<8;kk++){ sv[kk]=SC[r*8+kk]; m = fmaxf(m, sv[kk]); }
        float ssum = 0.f;
        #pragma unroll
        for(int kk=0;kk<8;kk++){ sv[kk]=__expf(sv[kk]-m); ssum += sv[kk]; }
        float inv = 1.f/ssum;
        float o[8] = {0.f,0.f,0.f,0.f,0.f,0.f,0.f,0.f};
        #pragma unroll
        for(int kk=0;kk<8;kk++){
          float pr = sv[kk]*inv;
          bfpack8 va; va.v = *(const short8*)&QH[(j*8+kk)*200 + 128 + p*8];
          #pragma unroll
          for(int ii=0;ii<8;ii++) o[ii] += pr * bf2f(va.u[ii]);
        }
        bfpack8 pk;
        #pragma unroll
        for(int ii=0;ii<8;ii++) pk.u[ii]=f2bf(o[ii]);
        *(short8*)(CTXb + (((unsigned)(r*512 + hh*128 + p*16)) ^ ((unsigned)(r&7)<<4))) = pk.v;
      }
      __syncthreads();
    }

    STAGE_WO(hg, 0, U);
    #pragma unroll
    for(int s=0; s<16; s++){
      int nh = s>>2, k2 = s&3;
      char* nxt = U + (((s+1)&1) ? 16384u : 0u);
      if(s<15) STAGE_WO(hg, s+1, nxt);
      if(s<15) asm volatile("s_waitcnt vmcnt(2)" ::: "memory");
      else     asm volatile("s_waitcnt vmcnt(0)" ::: "memory");
      FBAR();
      const char* bs = U + ((s&1) ? 16384u : 0u);
      int arow = mt*16+lm;
      #pragma unroll
      for(int half=0; half<2; half++){
        short8 a = *(const short8*)(CTXb + (unsigned)arow*512u
                     + (((unsigned)(k2*128 + half*64 + lg*16)) ^ ((unsigned)(arow&7)<<4)));
        #pragma unroll
        for(int i=0;i<4;i++){
          int brow = (wb*4+i)*16+lm;
          short8 bb = *(const short8*)(bs + (unsigned)brow*128u
                       + (((unsigned)(half*64+lg*16)) ^ ((unsigned)(brow&7)<<4)));
          acc2[nh][i] = MFMA_BF16(a, bb, acc2[nh][i]);
        }
      }
      FBAR();
    }
  }

  #pragma unroll
  for(int nh=0; nh<4; nh++)
    #pragma unroll
    for(int i=0;i<4;i++){
      int gcol = nh*128 + (wb*4+i)*16 + lm;
      float bia = bo[e*512 + gcol];
      #pragma unroll
      for(int rr=0;rr<4;rr++){
        int row = mt*16 + lg*4 + rr;
        int j2 = row>>3;
        int slot = (base+j2<ne)? jb[j2] : jb[0];
        int b = slot>>1, n = row&7;
        float tok = (gcol<256)? lat[((size_t)b*8+n)*256 + gcol]
                              : act[((size_t)b*8+n)*256 + gcol - 256];
        *(unsigned short*)(Abase + (((unsigned)(row*1024 + gcol*2)) ^ ((unsigned)(row&7)<<4)))
            = f2bf(acc2[nh][i][rr] + bia + tok);
      }
    }
  __syncthreads();
  {
    int r = t>>3, p = t&7;
    unsigned rsw = ((unsigned)(r&7))<<4;
    bfpack8 xv[8];
    float sum=0.f, sq=0.f;
    #pragma unroll
    for(int j=0;j<8;j++){
      xv[j].v = *(const short8*)(Abase + (((unsigned)(r*1024 + j*128 + p*16)) ^ rsw));
      #pragma unroll
      for(int ii=0;ii<8;ii++){ float f = bf2f(xv[j].u[ii]); sum += f; sq += f*f; }
    }
    sum += __shfl_xor(sum,1); sq += __shfl_xor(sq,1);
    sum += __shfl_xor(sum,2); sq += __shfl_xor(sq,2);
    sum += __shfl_xor(sum,4); sq += __shfl_xor(sq,4);
    float mu = sum*(1.f/512.f);
    float var = sq*(1.f/512.f) - mu*mu;
    float rstd = rsqrtf(var + LN_EPS);
    int j8 = r>>3;
    if(base + j8 < ne){
      int slot = jb[j8]; int n = r&7;
      unsigned short* dst = &x_bf[((size_t)slot*8+n)*512];
      #pragma unroll
      for(int j=0;j<8;j++){
        bfpack8 pk;
        #pragma unroll
        for(int ii=0;ii<8;ii++){
          int gc = j*64 + p*8 + ii;
          float xvv = (bf2f(xv[j].u[ii]) - mu)*rstd*ln1g[e*512+gc] + ln1b[e*512+gc];
          pk.u[ii] = f2bf(xvv);
        }
        *(short8*)&dst[j*64 + p*8] = pk.v;
      }
    }
  }
}

// ============ expert FFN v6: v4 geometry + TRIPLE-buffer slabs, ONE barrier/step ============
// 512 thr, 8 waves 2m x 4n; wave tile 32 rows x 64 cols. 256-col chunks (8), 32KB slabs.
// LDS: slabs 3 x 32KB @0/32768/65536, HC [64][264] bf16 @98304 (33792B).
// PL [64][520] overlays slabs (66560B) after K-loops.
// Safety: stage at step g targets buffer last read at step g-2; the FBAR(g-1) rendezvous
// (stage issued after issuing wave passed it => all waves' g-2 reads retired) makes the
// trailing barrier unnecessary. vmcnt counts: G1 step = 4 xf + 4 stage = 8; G2 = 4.
#define E2_LDS 132096
#define E2_HP  264

#define FFN_STAGE_W1(cc, kk, dstoff) do{ \
    unsigned _Lw = (unsigned)w*4096u; \
    _Pragma("unroll") \
    for(int _q=0;_q<4;_q++){ \
      unsigned _L = _Lw + (unsigned)_q*1024u + (unsigned)lane*16u; \
      int _row = (int)(_L>>7); unsigned _pb = _L&127u; \
      const char* _g = W1 + (size_t)((cc)*256+_row)*1024 + (kk)*128 + (_pb ^ ((unsigned)(_row&7)<<4)); \
      gload16(_g, smem + (dstoff) + _Lw + (unsigned)_q*1024u); \
    } }while(0)

#define FFN_STAGE_W2(cc, nn, kk, dstoff) do{ \
    unsigned _Lw = (unsigned)w*4096u; \
    _Pragma("unroll") \
    for(int _q=0;_q<4;_q++){ \
      unsigned _L = _Lw + (unsigned)_q*1024u + (unsigned)lane*16u; \
      int _row = (int)(_L>>7); unsigned _pb = _L&127u; \
      const char* _g = W2 + (size_t)((nn)*256+_row)*4096 + ((cc)*256+(kk)*64)*2 \
                     + (_pb ^ ((unsigned)(_row&7)<<4)); \
      gload16(_g, smem + (dstoff) + _Lw + (unsigned)_q*1024u); \
    } }while(0)

#define ROT3() do{ unsigned _tmp=cur; cur=nxt; nxt=spr; spr=_tmp; }while(0)

__global__ __launch_bounds__(512,2) void k_expert_ffn(
    const unsigned short* __restrict__ x_bf,
    const unsigned short* __restrict__ Wf1_t, const float* __restrict__ bf1,
    const unsigned short* __restrict__ Wf2_t, const float* __restrict__ bf2v,
    const float* __restrict__ ln2g, const float* __restrict__ ln2b,
    const int* __restrict__ jobs, const int* __restrict__ cnt,
    unsigned short* __restrict__ slot_out){
  extern __shared__ char smem[];
  unsigned short* HC = (unsigned short*)(smem + 98304);
  unsigned short* PL = (unsigned short*)smem;   // overlay after K-loops

  // balanced XCD map: XCD pair (2e,2e+1) owns expert e
  int bid = blockIdx.x;
  int e   = (bid&7)>>1;
  int blk = ((bid>>3)<<1) | (bid&1);
  int ne = cnt[e];
  int base = blk*8;
  if(base >= ne) return;
  int t = threadIdx.x;
  int w = t>>6, lane = t&63, lg = lane>>4, lm = lane&15;
  int mg = w>>2, ng = w&3;                    // 2m x 4n wave grid
  const int* jb = &jobs[e*2048 + base];
  unsigned bswz = ((unsigned)(lm&7))<<4;      // B-read swizzle (brow&7 == lm&7)

  const char* W1 = (const char*)(Wf1_t + (size_t)e*2048*512);
  const char* W2 = (const char*)(Wf2_t + (size_t)e*512*2048);

  // per-lane x base addresses for A-frags (row = mg*32 + ms*16 + lm)
  const char* xb[2];
  #pragma unroll
  for(int ms=0;ms<2;ms++){
    int row = mg*32 + ms*16 + lm;
    int j = row>>3;
    int slot = (base+j<ne)? jb[j] : jb[0];
    int n = row&7;
    xb[ms] = (const char*)x_bf + (((size_t)slot*8+n)<<10) + (size_t)(lg*16);
  }

  // x-frag double buffer: xf[parity][ms][half]
  short8 xf[2][2][2];
  #pragma unroll
  for(int ms=0;ms<2;ms++)
    #pragma unroll
    for(int hf=0;hf<2;hf++)
      xf[0][ms][hf] = *(const short8*)(xb[ms] + hf*64);

  f32x4 acc[2][2][4];   // [nh][ms][ns] persistent G2 accumulator
  #pragma unroll
  for(int a=0;a<2;a++)
    #pragma unroll
    for(int b=0;b<2;b++)
      #pragma unroll
      for(int c2=0;c2<4;c2++) acc[a][b][c2]=(f32x4){0.f,0.f,0.f,0.f};

  unsigned cur=0u, nxt=32768u, spr=65536u;

  // prologue: stage step-0 slab into cur (4 loads; forced by first vmcnt(8))
  FFN_STAGE_W1(0, 0, cur);

  for(int c=0; c<8; c++){
    f32x4 acc1[2][4];
    #pragma unroll
    for(int b=0;b<2;b++)
      #pragma unroll
      for(int c2=0;c2<4;c2++) acc1[b][c2]=(f32x4){0.f,0.f,0.f,0.f};

    // ---- G1: 8 steps, BK=64
    #pragma unroll
    for(int ks=0; ks<8; ks++){
      // x-frag prefetch FIRST (keeps reg-dep waits loose)
      #pragma unroll
      for(int ms=0;ms<2;ms++)
        #pragma unroll
        for(int hf=0;hf<2;hf++)
          xf[(ks+1)&1][ms][hf] = *(const short8*)(xb[ms] + (((ks+1)&7)*128 + hf*64));
      if(ks<7) FFN_STAGE_W1(c, ks+1, nxt);
      else     FFN_STAGE_W2(c, 0, 0, nxt);
      asm volatile("s_waitcnt vmcnt(8)" ::: "memory");   // prev step's 8 (stage+xf) landed
      FBAR();
      const char* bs = smem + cur;
      #pragma unroll
      for(int hf=0;hf<2;hf++){
        #pragma unroll
        for(int ns=0;ns<4;ns++){
          unsigned boff = (unsigned)(((ng*4+ns)*16+lm)*128);
          short8 bb = *(const short8*)(bs + boff + (((unsigned)(hf*64+lg*16)) ^ bswz));
          acc1[0][ns] = MFMA_BF16(xf[ks&1][0][hf], bb, acc1[0][ns]);
          acc1[1][ns] = MFMA_BF16(xf[ks&1][1][hf], bb, acc1[1][ns]);
        }
      }
      if(ks==7){
        // HC write: h_c = relu(acc1 + bf1)
        #pragma unroll
        for(int ms=0;ms<2;ms++)
          #pragma unroll
          for(int ns=0;ns<4;ns++){
            int colL = ng*64 + ns*16 + lm;
            float bia = bf1[e*2048 + c*256 + colL];
            #pragma unroll
            for(int rr=0;rr<4;rr++){
              int row = mg*32 + ms*16 + lg*4 + rr;
              HC[row*E2_HP + colL] = f2bf(fmaxf(acc1[ms][ns][rr] + bia, 0.f));
            }
          }
        asm volatile("s_waitcnt lgkmcnt(0)" ::: "memory");  // flush HC before next FBAR
      }
      ROT3();
    }

    // ---- G2: 8 steps (nh*4+k2)
    #pragma unroll
    for(int s2=0; s2<8; s2++){
      const int nh = s2>>2, k2 = s2&3;
      if(s2<7)      FFN_STAGE_W2(c, (s2+1)>>2, (s2+1)&3, nxt);
      else if(c<7)  FFN_STAGE_W1(c+1, 0, nxt);
      if(s2==7 && c==7) asm volatile("s_waitcnt vmcnt(0)" ::: "memory");
      else              asm volatile("s_waitcnt vmcnt(4)" ::: "memory");
      FBAR();
      const char* bs = smem + cur;
      #pragma unroll
      for(int hf=0;hf<2;hf++){
        short8 ha0 = *(const short8*)&HC[(mg*32 +      lm)*E2_HP + k2*64 + hf*32 + lg*8];
        short8 ha1 = *(const short8*)&HC[(mg*32 + 16 + lm)*E2_HP + k2*64 + hf*32 + lg*8];
        #pragma unroll
        for(int ns=0;ns<4;ns++){
          unsigned boff = (unsigned)(((ng*4+ns)*16+lm)*128);
          short8 bb = *(const short8*)(bs + boff + (((unsigned)(hf*64+lg*16)) ^ bswz));
          acc[nh][0][ns] = MFMA_BF16(ha0, bb, acc[nh][0][ns]);
          acc[nh][1][ns] = MFMA_BF16(ha1, bb, acc[nh][1][ns]);
        }
      }
      ROT3();
    }
  }
  __syncthreads();   // all slab/HC reads retired before PL overlay

  // ---- PL = acc + bf2 (residual added in LN phase from global) ----
  #pragma unroll
  for(int nh=0;nh<2;nh++)
    #pragma unroll
    for(int ms=0;ms<2;ms++)
      #pragma unroll
      for(int ns=0;ns<4;ns++){
        int col = nh*256 + ng*64 + ns*16 + lm;
        float bia = bf2v[e*512+col];
        #pragma unroll
        for(int rr=0;rr<4;rr++){
          int row = mg*32 + ms*16 + lg*4 + rr;
          PL[row*520 + col] = f2bf(acc[nh][ms][ns][rr] + bia);
        }
      }
  __syncthreads();

  // ---- LN2 (+global residual) -> slot_out ----
  {
    int r = t>>3, p = t&7;
    int j8 = r>>3;
    int slot = (base + j8 < ne) ? jb[j8] : jb[0];
    int n = r&7;
    const unsigned short* xg = &x_bf[((size_t)slot*8+n)*512];
    bfpack8 cv[8];
    float sum=0.f, sq=0.f;
    #pragma unroll
    for(int j=0;j<8;j++){
      bfpack8 pa; pa.v = *(const short8*)&PL[r*520 + j*64 + p*8];
      bfpack8 xa; xa.v = *(const short8*)&xg[j*64 + p*8];
      #pragma unroll
      for(int ii=0;ii<8;ii++){
        float f = bf2f(pa.u[ii]) + bf2f(xa.u[ii]);
        cv[j].u[ii] = f2bf(f);
        f = bf2f(cv[j].u[ii]);
        sum += f; sq += f*f;
      }
    }
    sum += __shfl_xor(sum,1); sq += __shfl_xor(sq,1);
    sum += __shfl_xor(sum,2); sq += __shfl_xor(sq,2);
    sum += __shfl_xor(sum,4); sq += __shfl_xor(sq,4);
    float mu = sum*(1.f/512.f);
    float var = sq*(1.f/512.f) - mu*mu;
    float rstd = rsqrtf(var + LN_EPS);
    if(base + j8 < ne){
      unsigned short* dst = &slot_out[((size_t)slot*8+n)*512];
      #pragma unroll
      for(int j=0;j<8;j++){
        bfpack8 pk;
        #pragma unroll
        for(int ii=0;ii<8;ii++){
          int gc = j*64 + p*8 + ii;
          float xv = (bf2f(cv[j].u[ii]) - mu)*rstd*ln2g[e*512+gc] + ln2b[e*512+gc];
          pk.u[ii] = f2bf(xv);
        }
        *(short8*)&dst[j*64 + p*8] = pk.v;
      }
    }
  }
}

// ============ combine: mixed_bf[b][d] = w0*out[2b][d] + w1*out[2b+1][d] ============
__global__ __launch_bounds__(256) void k_combine(const unsigned short* __restrict__ so,
    const float* __restrict__ slotw, unsigned short* __restrict__ mx){
  int gid = blockIdx.x*256 + threadIdx.x;
  int b = gid >> 9, c8 = gid & 511;
  float w0 = slotw[b*2+0], w1 = slotw[b*2+1];
  bfpack8 x0; x0.v = *(const short8*)&so[((size_t)(b*2+0))*4096 + c8*8];
  bfpack8 x1; x1.v = *(const short8*)&so[((size_t)(b*2+1))*4096 + c8*8];
  bfpack8 o;
  #pragma unroll
  for(int j=0;j<8;j++) o.u[j] = f2bf(w0*bf2f(x0.u[j]) + w1*bf2f(x1.u[j]));
  *(short8*)&mx[(size_t)b*4096 + c8*8] = o.v;
}

// ============ head GEMM 1: hidden = relu(mixed_bf @ hW1 + b1) ============
#define H_SP 72
__global__ __launch_bounds__(256) void k_head1(const unsigned short* __restrict__ mixbf,
    const unsigned short* __restrict__ hW1t, const float* __restrict__ b1,
    unsigned short* __restrict__ hidden){
  __shared__ unsigned short As[64*H_SP], Bs[64*H_SP];
  int n0 = blockIdx.x*64, m0 = blockIdx.y*64;
  int t = threadIdx.x, w = t>>6, lane = t&63, lg = lane>>4, lm = lane&15;
  f32x4 acc[4]; for(int i=0;i<4;i++) acc[i]=(f32x4){0.f,0.f,0.f,0.f};
  for(int ks=0; ks<64; ks++){
    __syncthreads();
    int k0 = ks*64;
    for(int i=0;i<2;i++){
      int u = i*256 + t; int row = u>>3, ch = u&7;
      *(short8*)&As[row*H_SP + ch*8] = *(const short8*)&mixbf[(size_t)(m0+row)*4096 + k0 + ch*8];
    }
    for(int i=0;i<2;i++){
      int u = i*256 + t; int row = u>>3, ch = u&7;
      *(short8*)&Bs[row*H_SP + ch*8] = *(const short8*)&hW1t[(size_t)(n0+row)*4096 + k0 + ch*8];
    }
    __syncthreads();
    for(int half=0; half<2; half++){
      short8 a = *(const short8*)&As[(w*16+lm)*H_SP + half*32 + lg*8];
      for(int i=0;i<4;i++){
        short8 bb = *(const short8*)&Bs[(i*16+lm)*H_SP + half*32 + lg*8];
        acc[i] = MFMA_BF16(a, bb, acc[i]);
      }
    }
  }
  for(int i=0;i<4;i++){
    int gc = n0 + i*16 + lm; float bia = b1[gc];
    for(int rr=0; rr<4; rr++){
      int row = m0 + w*16 + lg*4 + rr;
      hidden[(size_t)row*512 + gc] = f2bf(fmaxf(acc[i][rr] + bia, 0.f));
    }
  }
}

// ============ head GEMM 2: logits = hidden @ hW2 + b2 ============
__global__ __launch_bounds__(256) void k_head2(const unsigned short* __restrict__ hidden,
    const unsigned short* __restrict__ hW2t, const float* __restrict__ b2,
    float* __restrict__ out){
  __shared__ unsigned short As[64*H_SP], Bs[112*H_SP];
  int m0 = blockIdx.x*64;
  int t = threadIdx.x, w = t>>6, lane = t&63, lg = lane>>4, lm = lane&15;
  f32x4 acc[7]; for(int i=0;i<7;i++) acc[i]=(f32x4){0.f,0.f,0.f,0.f};
  for(int ks=0; ks<8; ks++){
    __syncthreads();
    int k0 = ks*64;
    for(int i=0;i<2;i++){
      int u = i*256 + t; int row = u>>3, ch = u&7;
      *(short8*)&As[row*H_SP + ch*8] = *(const short8*)&hidden[(size_t)(m0+row)*512 + k0 + ch*8];
    }
    for(int i=0;i<4;i++){
      int u = i*256 + t;
      if(u < 896){
        int row = u>>3, ch = u&7;
        *(short8*)&Bs[row*H_SP + ch*8] = *(const short8*)&hW2t[(size_t)row*512 + k0 + ch*8];
      }
    }
    __syncthreads();
    for(int half=0; half<2; half++){
      short8 a = *(const short8*)&As[(w*16+lm)*H_SP + half*32 + lg*8];
      for(int i=0;i<7;i++){
        short8 bb = *(const short8*)&Bs[(i*16+lm)*H_SP + half*32 + lg*8];
        acc[i] = MFMA_BF16(a, bb, acc[i]);
      }
    }
  }
  for(int i=0;i<7;i++){
    int col = i*16 + lm;
    if(col < 101){
      float bia = b2[col];
      for(int rr=0; rr<4; rr++){
        int row = m0 + w*16 + lg*4 + rr;
        out[(size_t)row*101 + col] = acc[i][rr] + bia;
      }
    }
  }
}

// ================= host launcher =================
extern "C" void kernel_launch(void* const* d_in, const int* in_sizes, int n_in,
                              void* d_out, int out_size, void* d_ws, size_t ws_size,
                              hipStream_t stream){
  if(ws_size < WS_NEED) return;
  const float* lat  = (const float*)d_in[0];
  const float* act  = (const float*)d_in[1];
  const float* gateW= (const float*)d_in[2];
  const float* Wqkv = (const float*)d_in[3];
  const float* bqkv = (const float*)d_in[4];
  const float* Wo   = (const float*)d_in[5];
  const float* bo   = (const float*)d_in[6];
  const float* ln1g = (const float*)d_in[7];
  const float* ln1b = (const float*)d_in[8];
  const float* Wf1  = (const float*)d_in[9];
  const float* bf1  = (const float*)d_in[10];
  const float* Wf2  = (const float*)d_in[11];
  const float* bf2v = (const float*)d_in[12];
  const float* ln2g = (const float*)d_in[13];
  const float* ln2b = (const float*)d_in[14];
  const float* hW1  = (const float*)d_in[15];
  const float* hb1  = (const float*)d_in[16];
  const float* hW2  = (const float*)d_in[17];
  const float* hb2  = (const float*)d_in[18];
  float* out = (float*)d_out;
  char* ws = (char*)d_ws;

  unsigned short* WQKVT = (unsigned short*)(ws + OFF_WQKVT);
  unsigned short* WOT   = (unsigned short*)(ws + OFF_WOT);
  unsigned short* WF1T  = (unsigned short*)(ws + OFF_WF1T);
  unsigned short* WF2T  = (unsigned short*)(ws + OFF_WF2T);
  unsigned short* HW1T  = (unsigned short*)(ws + OFF_HW1T);
  unsigned short* HW2T  = (unsigned short*)(ws + OFF_HW2T);
  unsigned short* XBF   = (unsigned short*)(ws + OFF_XBF);   // x after LN1; reused as MIXEDBF
  unsigned short* SLOTO = (unsigned short*)(ws + OFF_SLOTO);
  unsigned short* MIXBF = XBF;
  unsigned short* HID = (unsigned short*)(ws + OFF_HID);
  int* JOBS = (int*)(ws + OFF_JOBS);
  float* SLOTW = (float*)(ws + OFF_SLOTW);
  float* LSE = (float*)(ws + OFF_LSE);
  int* CNT = (int*)(ws + OFF_CNT);

  (void)hipFuncSetAttribute((const void*)k_expert_attn,
      hipFuncAttributeMaxDynamicSharedMemorySize, AT_LDS);
  (void)hipFuncSetAttribute((const void*)k_expert_ffn,
      hipFuncAttributeMaxDynamicSharedMemorySize, E2_LDS);

  hipMemsetAsync(CNT, 0, 16, stream);
  hipMemsetAsync(HW2T, 0, 112*512*2, stream);

  // weight transposes (fp32 -> bf16, [R][C] -> [C][R])
  k_transpose_cast<<<dim3(48,16,4),256,0,stream>>>(Wqkv, WQKVT, 512, 1536);
  k_transpose_cast<<<dim3(16,16,4),256,0,stream>>>(Wo,   WOT,   512, 512);
  k_transpose_cast<<<dim3(64,16,4),256,0,stream>>>(Wf1,  WF1T,  512, 2048);
  k_transpose_cast<<<dim3(16,64,4),256,0,stream>>>(Wf2,  WF2T,  2048, 512);
  k_transpose_cast<<<dim3(16,128,1),256,0,stream>>>(hW1, HW1T,  4096, 512);
  k_transpose_cast<<<dim3(4,16,1),256,0,stream>>>(hW2,  HW2T,  512, 101);

  k_router<<<2048,256,0,stream>>>(lat, act, gateW, out + OUT_GATES, JOBS, CNT, SLOTW, LSE);
  k_finalize<<<1,256,0,stream>>>(out + OUT_GATES, LSE, CNT, out + OUT_LBL);

  k_expert_attn<<<1024, 512, AT_LDS, stream>>>(lat, act, WQKVT, bqkv, WOT, bo,
      ln1g, ln1b, JOBS, CNT, XBF);
  k_expert_ffn<<<1024, 512, E2_LDS, stream>>>(XBF, WF1T, bf1, WF2T, bf2v,
      ln2g, ln2b, JOBS, CNT, SLOTO);
  k_combine<<<4096,256,0,stream>>>(SLOTO, SLOTW, MIXBF);

  k_head1<<<dim3(8,32),256,0,stream>>>(MIXBF, HW1T, hb1, HID);
  k_head2<<<32,256,0,stream>>>(HID, HW2T, hb2, out);
}